// Round 3
// baseline (889.743 us; speedup 1.0000x reference)
//
#include <hip/hip_runtime.h>
#include <stdint.h>

// ===================== problem constants =====================
constexpr int D_MODEL = 768;
constexpr int SEQ     = 4096;
constexpr int NHEAD   = 12;
constexpr int HDIM    = 64;
constexpr int BATCH   = 2;
constexpr int DFF     = 3072;
constexpr int ROWS    = BATCH * SEQ;   // 8192

typedef __attribute__((ext_vector_type(8))) __bf16 bfrag;
typedef __attribute__((ext_vector_type(8))) short  s16x8;
typedef __attribute__((ext_vector_type(4))) float  f32x4;

#define MFMA16(a, b, c) __builtin_amdgcn_mfma_f32_16x16x32_bf16((a), (b), (c), 0, 0, 0)

__device__ __forceinline__ float b2f(short s) {
  union { unsigned u; float f; } c;
  c.u = ((unsigned)(unsigned short)s) << 16;
  return c.f;
}
__device__ __forceinline__ short f2b(float f) {
  union { float f; unsigned u; } c;
  c.f = f;
  unsigned r = c.u + 0x7fffu + ((c.u >> 16) & 1u);  // RNE (finite inputs only)
  return (short)(r >> 16);
}
// dtype-flexible external load/store (flag: 1 = fp32, 0 = bf16)
__device__ __forceinline__ float ldf(const void* p, size_t i, bool f32) {
  return f32 ? ((const float*)p)[i] : b2f(((const short*)p)[i]);
}
__device__ __forceinline__ void stf(void* p, size_t i, bool f32, float v) {
  if (f32) ((float*)p)[i] = v;
  else     ((short*)p)[i] = f2b(v);
}

// ===================== dtype probe =====================
// ln1_scale is all-ones. bf16: first u16 == 0x3F80. fp32: first u16 == 0x0000.
__global__ void probe_kernel(const unsigned short* __restrict__ s, int* __restrict__ flag) {
  *flag = (s[0] == 0x3F80u) ? 0 : 1;
}

// ===================== static BigBird plan (constexpr MT19937 == np.random.RandomState(0)) =====================
struct PlanT { int v[64][8]; };

struct MTRng {
  unsigned mt[624];
  int mti;
  constexpr MTRng() : mt{}, mti(624) {
    mt[0] = 0u;
    for (int i = 1; i < 624; ++i)
      mt[i] = 1812433253u * (mt[i-1] ^ (mt[i-1] >> 30)) + (unsigned)i;
  }
  constexpr unsigned next() {
    if (mti >= 624) {
      for (int i = 0; i < 624; ++i) {
        unsigned y = (mt[i] & 0x80000000u) | (mt[(i+1) % 624] & 0x7fffffffu);
        unsigned v = mt[(i+397) % 624] ^ (y >> 1);
        if (y & 1u) v ^= 0x9908b0dfu;
        mt[i] = v;
      }
      mti = 0;
    }
    unsigned y = mt[mti++];
    y ^= y >> 11;
    y ^= (y << 7)  & 0x9d2c5680u;
    y ^= (y << 15) & 0xefc60000u;
    y ^= y >> 18;
    return y;
  }
  constexpr unsigned interval(unsigned mx) {  // numpy rk_interval: [0, mx]
    unsigned mask = mx;
    mask |= mask >> 1; mask |= mask >> 2; mask |= mask >> 4;
    mask |= mask >> 8; mask |= mask >> 16;
    unsigned v = next() & mask;
    while (v > mx) v = next() & mask;
    return v;
  }
};

constexpr PlanT make_plan() {
  PlanT P{};
  MTRng rng{};
  for (int i = 1; i <= 62; ++i) {
    int cand[64] = {}; int n = 0;
    for (int j = 0; j < 64; ++j) {
      if (j == 0 || j == 63 || j == i-1 || j == i || j == i+1) continue;
      cand[n++] = j;
    }
    int perm[64] = {};
    for (int p = 0; p < n; ++p) perm[p] = p;
    for (int p = n - 1; p > 0; --p) {           // numpy shuffle (choice replace=False)
      int j = (int)rng.interval((unsigned)p);
      int t = perm[p]; perm[p] = perm[j]; perm[j] = t;
    }
    P.v[i][0] = 0;  P.v[i][1] = 63; P.v[i][2] = i-1; P.v[i][3] = i; P.v[i][4] = i+1;
    P.v[i][5] = cand[perm[0]]; P.v[i][6] = cand[perm[1]]; P.v[i][7] = cand[perm[2]];
  }
  return P;
}
constexpr PlanT h_plan = make_plan();
__constant__ PlanT g_plan = h_plan;

// ===================== layernorm (external-dtype in, bf16 out) =====================
__global__ __launch_bounds__(256) void ln_kernel(
    const void* __restrict__ x, const void* __restrict__ sc,
    const void* __restrict__ bi, short* __restrict__ y,
    const int* __restrict__ flagp)
{
  const bool f32 = (*flagp != 0);
  const int row = blockIdx.x, tid = threadIdx.x;
  const size_t base = (size_t)row * D_MODEL;
  float v0 = ldf(x, base + tid,       f32);
  float v1 = ldf(x, base + tid + 256, f32);
  float v2 = ldf(x, base + tid + 512, f32);
  float s  = v0 + v1 + v2;
  float s2 = v0*v0 + v1*v1 + v2*v2;
  for (int off = 1; off < 64; off <<= 1) {
    s  += __shfl_xor(s,  off);
    s2 += __shfl_xor(s2, off);
  }
  __shared__ float red[8];
  if ((tid & 63) == 0) { red[tid >> 6] = s; red[4 + (tid >> 6)] = s2; }
  __syncthreads();
  s  = red[0] + red[1] + red[2] + red[3];
  s2 = red[4] + red[5] + red[6] + red[7];
  const float mu  = s * (1.f / 768.f);
  const float var = s2 * (1.f / 768.f) - mu * mu;
  const float rs  = rsqrtf(var + 1e-6f);
  short* yr = y + base;
  yr[tid]       = f2b((v0 - mu) * rs * ldf(sc, tid,       f32) + ldf(bi, tid,       f32));
  yr[tid + 256] = f2b((v1 - mu) * rs * ldf(sc, tid + 256, f32) + ldf(bi, tid + 256, f32));
  yr[tid + 512] = f2b((v2 - mu) * rs * ldf(sc, tid + 512, f32) + ldf(bi, tid + 512, f32));
}

// ===================== transpose external weight (R x C -> bf16 C x R) =====================
__global__ __launch_bounds__(256) void tr_kernel(
    const void* __restrict__ in, short* __restrict__ out, int R, int C,
    const int* __restrict__ flagp)
{
  const bool f32 = (*flagp != 0);
  __shared__ short tile[32][33];
  const int bx = blockIdx.x * 32, by = blockIdx.y * 32;
  const int tx = threadIdx.x, ty = threadIdx.y;
  for (int i = 0; i < 32; i += 8)
    tile[ty + i][tx] = f2b(ldf(in, (size_t)(by + ty + i) * C + bx + tx, f32));
  __syncthreads();
  for (int i = 0; i < 32; i += 8)
    out[(size_t)(bx + ty + i) * R + by + tx] = tile[tx][ty + i];
}

// ===================== GEMM: C[M,N] = A[M,K] @ Bt[N,K]^T, bf16 internal, fp32 acc =====================
// Register-mediated staging (global->reg, barrier, reg->LDS, barrier).
enum { M_PLAIN = 0, M_SCALE = 1, M_VT = 2, M_RES = 3, M_BRELU = 4, M_BRES = 5 };

template <int MODE>
__global__ __launch_bounds__(256) void gemm_bt(
    const short* __restrict__ A, const short* __restrict__ Bt,
    void* __restrict__ Cv, const void* __restrict__ res,
    const void* __restrict__ bias, int N, int K,
    const int* __restrict__ flagp)
{
  const bool f32 = (*flagp != 0);
  alignas(16) __shared__ short As[128 * 32];
  alignas(16) __shared__ short Bs[128 * 32];
  const int tid = threadIdx.x;
  const int wave = tid >> 6, lane = tid & 63;
  const int quad = lane >> 4, l15 = lane & 15;
  const int m0 = blockIdx.x * 128, n0 = blockIdx.y * 128;
  const int mw = (wave & 1) * 64, nw = (wave >> 1) * 64;

  f32x4 acc[4][4];
#pragma unroll
  for (int i = 0; i < 4; ++i)
#pragma unroll
    for (int j = 0; j < 4; ++j) acc[i][j] = f32x4{0.f, 0.f, 0.f, 0.f};

  const int r1 = tid >> 2;            // 0..63
  const int c1 = (tid & 3) * 8;       // 0,8,16,24
  const short* Ap0 = A  + (size_t)(m0 + r1)      * K + c1;
  const short* Ap1 = A  + (size_t)(m0 + r1 + 64) * K + c1;
  const short* Bp0 = Bt + (size_t)(n0 + r1)      * K + c1;
  const short* Bp1 = Bt + (size_t)(n0 + r1 + 64) * K + c1;

  for (int k0 = 0; k0 < K; k0 += 32) {
    const s16x8 a0 = *(const s16x8*)(Ap0 + k0);
    const s16x8 a1 = *(const s16x8*)(Ap1 + k0);
    const s16x8 b0 = *(const s16x8*)(Bp0 + k0);
    const s16x8 b1 = *(const s16x8*)(Bp1 + k0);
    __syncthreads();  // previous tile fully consumed
    *(s16x8*)(As + r1 * 32 + c1)        = a0;
    *(s16x8*)(As + (r1 + 64) * 32 + c1) = a1;
    *(s16x8*)(Bs + r1 * 32 + c1)        = b0;
    *(s16x8*)(Bs + (r1 + 64) * 32 + c1) = b1;
    __syncthreads();  // staging complete
    bfrag af[4], bfv[4];
#pragma unroll
    for (int mt = 0; mt < 4; ++mt) af[mt]  = *(const bfrag*)(As + (mw + mt*16 + l15) * 32 + quad * 8);
#pragma unroll
    for (int nt = 0; nt < 4; ++nt) bfv[nt] = *(const bfrag*)(Bs + (nw + nt*16 + l15) * 32 + quad * 8);
#pragma unroll
    for (int mt = 0; mt < 4; ++mt)
#pragma unroll
      for (int nt = 0; nt < 4; ++nt)
        acc[mt][nt] = MFMA16(af[mt], bfv[nt], acc[mt][nt]);
  }

  // epilogue: C/D layout col = lane&15, row = quad*4 + reg  [m89-verified]
#pragma unroll
  for (int mt = 0; mt < 4; ++mt) {
#pragma unroll
    for (int nt = 0; nt < 4; ++nt) {
#pragma unroll
      for (int r = 0; r < 4; ++r) {
        const int gm = m0 + mw + mt*16 + quad*4 + r;
        const int gn = n0 + nw + nt*16 + l15;
        const size_t ci = (size_t)gm * N + gn;
        float v = acc[mt][nt][r];
        if (MODE == M_SCALE) v *= 0.125f;                                    // q / sqrt(HD)
        if (MODE == M_RES)   v += ldf(res, ci, f32);                         // + x (external)
        if (MODE == M_BRELU) { v += ldf(bias, gn, f32); v = v > 0.f ? v : 0.f; } // + b1, relu
        if (MODE == M_BRES)  v += ldf(bias, gn, f32) + ldf(res, ci, f32);    // + b2 + x1 (in d_out)
        if (MODE == M_VT) {
          // scatter V into Vt[b][h][hd][l]  (BT-form operand for PV) -- internal bf16
          const int bb = gm >> 12, l = gm & 4095, hh = gn >> 6, hd = gn & 63;
          ((short*)Cv)[(((size_t)(bb * NHEAD + hh)) * HDIM + hd) * SEQ + l] = f2b(v);
        } else if (MODE == M_RES || MODE == M_BRES) {
          stf(Cv, ci, f32, v);        // d_out: external dtype
        } else {
          ((short*)Cv)[ci] = f2b(v);  // internal bf16
        }
      }
    }
  }
}

// ===================== flash-style BigBird attention (all internal bf16) =====================
// grid (qblock=64, head=12, batch=2), 256 threads = 4 waves; wave w owns q-rows [w*16, w*16+16).
__global__ __launch_bounds__(256) void attn_kernel(
    const short* __restrict__ q, const short* __restrict__ k,
    const short* __restrict__ vt, short* __restrict__ o)
{
  alignas(16) __shared__ short Pbuf[4][16 * 64];  // per-wave P tile (A-layout)
  const int qb = blockIdx.x, h = blockIdx.y, b = blockIdx.z;
  const int tid = threadIdx.x, wave = tid >> 6, lane = tid & 63;
  const int quad = lane >> 4, l15 = lane & 15;

  const bool glob = (qb == 0 || qb == 63);
  const int nkb = glob ? 64 : 8;

  const short* qp = q + (size_t)(b * SEQ + qb * 64 + wave * 16 + l15) * D_MODEL + h * HDIM;
  const bfrag qf0 = *(const bfrag*)(qp + quad * 8);
  const bfrag qf1 = *(const bfrag*)(qp + 32 + quad * 8);

  const short* kb_base = k  + (size_t)b * SEQ * D_MODEL + h * HDIM;
  const short* vt_base = vt + ((size_t)(b * NHEAD + h)) * HDIM * SEQ;

  float m_r[4], l_r[4];
  f32x4 oacc[4];
#pragma unroll
  for (int r = 0; r < 4; ++r) { m_r[r] = -1e9f; l_r[r] = 0.f; }
#pragma unroll
  for (int nt = 0; nt < 4; ++nt) oacc[nt] = f32x4{0.f, 0.f, 0.f, 0.f};

  short* pb = &Pbuf[wave][0];

  for (int it = 0; it < nkb; ++it) {
    const int kbk = glob ? it : g_plan.v[qb][it];

    // ---- S = Q K^T (16 x 64) ----
    f32x4 sacc[4];
#pragma unroll
    for (int nt = 0; nt < 4; ++nt) sacc[nt] = f32x4{0.f, 0.f, 0.f, 0.f};
    {
      const short* kr = kb_base + ((size_t)kbk * 64 + l15) * D_MODEL + quad * 8;
#pragma unroll
      for (int nt = 0; nt < 4; ++nt) {
        const bfrag kf0 = *(const bfrag*)(kr + (size_t)nt * 16 * D_MODEL);
        const bfrag kf1 = *(const bfrag*)(kr + (size_t)nt * 16 * D_MODEL + 32);
        sacc[nt] = MFMA16(qf0, kf0, sacc[nt]);
        sacc[nt] = MFMA16(qf1, kf1, sacc[nt]);
      }
    }

    // ---- online softmax update (row = quad*4 + r, reduce over lane&15) ----
    float alpha[4];
#pragma unroll
    for (int r = 0; r < 4; ++r) {
      float v = fmaxf(fmaxf(sacc[0][r], sacc[1][r]), fmaxf(sacc[2][r], sacc[3][r]));
      v = fmaxf(v, __shfl_xor(v, 1));
      v = fmaxf(v, __shfl_xor(v, 2));
      v = fmaxf(v, __shfl_xor(v, 4));
      v = fmaxf(v, __shfl_xor(v, 8));
      const float mn = fmaxf(m_r[r], v);
      alpha[r] = __expf(m_r[r] - mn);
      m_r[r] = mn;
    }
    float psum[4] = {0.f, 0.f, 0.f, 0.f};
#pragma unroll
    for (int nt = 0; nt < 4; ++nt)
#pragma unroll
      for (int r = 0; r < 4; ++r) {
        const float p = __expf(sacc[nt][r] - m_r[r]);
        sacc[nt][r] = p;
        psum[r] += p;
      }
#pragma unroll
    for (int r = 0; r < 4; ++r) {
      float v = psum[r];
      v += __shfl_xor(v, 1); v += __shfl_xor(v, 2);
      v += __shfl_xor(v, 4); v += __shfl_xor(v, 8);
      l_r[r] = l_r[r] * alpha[r] + v;
    }

    // ---- P: C-layout -> A-layout via per-wave LDS ----
#pragma unroll
    for (int nt = 0; nt < 4; ++nt)
#pragma unroll
      for (int r = 0; r < 4; ++r)
        pb[(quad * 4 + r) * 64 + nt * 16 + l15] = f2b(sacc[nt][r]);
    __syncthreads();

    // ---- O = alpha*O + P V ----
#pragma unroll
    for (int nt = 0; nt < 4; ++nt)
#pragma unroll
      for (int r = 0; r < 4; ++r) oacc[nt][r] *= alpha[r];
    const short* vp = vt_base + (size_t)kbk * 64 + quad * 8;
#pragma unroll
    for (int s = 0; s < 2; ++s) {
      const bfrag pf = *(const bfrag*)(pb + l15 * 64 + s * 32 + quad * 8);
#pragma unroll
      for (int nt = 0; nt < 4; ++nt) {
        const bfrag vf = *(const bfrag*)(vp + (size_t)(nt * 16 + l15) * SEQ + s * 32);
        oacc[nt] = MFMA16(pf, vf, oacc[nt]);
      }
    }
    __syncthreads();  // P buffer free for next iteration
  }

  // ---- write O / l ----
  short* op = o + (size_t)(b * SEQ + qb * 64 + wave * 16) * D_MODEL + h * HDIM;
#pragma unroll
  for (int r = 0; r < 4; ++r) {
    const float inv = 1.f / l_r[r];
#pragma unroll
    for (int nt = 0; nt < 4; ++nt)
      op[(size_t)(quad * 4 + r) * D_MODEL + nt * 16 + l15] = f2b(oacc[nt][r] * inv);
  }
}

// ===================== launch =====================
extern "C" void kernel_launch(void* const* d_in, const int* in_sizes, int n_in,
                              void* d_out, int out_size, void* d_ws, size_t ws_size,
                              hipStream_t stream) {
  (void)in_sizes; (void)n_in; (void)out_size; (void)ws_size;
  const void* x    = d_in[0];
  const void* ln1s = d_in[1];
  const void* ln1b = d_in[2];
  const void* Wq   = d_in[3];
  const void* Wk   = d_in[4];
  const void* Wv   = d_in[5];
  const void* Wo   = d_in[6];
  const void* ln2s = d_in[7];
  const void* ln2b = d_in[8];
  const void* W1   = d_in[9];
  const void* b1   = d_in[10];
  const void* W2   = d_in[11];
  const void* b2   = d_in[12];

  // ws layout (~77.1 MiB): flag | weightsT (14.2) | hbuf (12.6) | BIG 4x12.6 (tbuf)
  int*   flagp = (int*)d_ws;
  short* WqT  = (short*)((char*)d_ws + 256);
  short* WkT  = WqT  + 768 * 768;
  short* WvT  = WkT  + 768 * 768;
  short* WoT  = WvT  + 768 * 768;
  short* W1T  = WoT  + 768 * 768;          // (3072,768)
  short* W2T  = W1T  + (size_t)3072 * 768; // (768,3072)
  short* hbuf = W2T  + (size_t)3072 * 768;
  short* qbuf = hbuf + (size_t)ROWS * D_MODEL;
  short* kbuf = qbuf + (size_t)ROWS * D_MODEL;
  short* vtb  = kbuf + (size_t)ROWS * D_MODEL;
  short* obuf = vtb  + (size_t)ROWS * D_MODEL;
  short* tbuf = qbuf;   // MLP intermediate spans qbuf..obuf (4*ROWS*D_MODEL == ROWS*DFF)
  void*  x1b  = d_out;  // attn + x residual lives in d_out (external dtype)

  probe_kernel<<<1, 1, 0, stream>>>((const unsigned short*)ln1s, flagp);

  const dim3 trb(32, 8);
  tr_kernel<<<dim3(24, 24), trb, 0, stream>>>(Wq, WqT, 768, 768, flagp);
  tr_kernel<<<dim3(24, 24), trb, 0, stream>>>(Wk, WkT, 768, 768, flagp);
  tr_kernel<<<dim3(24, 24), trb, 0, stream>>>(Wv, WvT, 768, 768, flagp);
  tr_kernel<<<dim3(24, 24), trb, 0, stream>>>(Wo, WoT, 768, 768, flagp);
  tr_kernel<<<dim3(96, 24), trb, 0, stream>>>(W1, W1T, 768, 3072, flagp);
  tr_kernel<<<dim3(24, 96), trb, 0, stream>>>(W2, W2T, 3072, 768, flagp);

  ln_kernel<<<ROWS, 256, 0, stream>>>(x, ln1s, ln1b, hbuf, flagp);

  gemm_bt<M_SCALE><<<dim3(64, 6), 256, 0, stream>>>(hbuf, WqT, qbuf, nullptr, nullptr, 768, 768, flagp);
  gemm_bt<M_PLAIN><<<dim3(64, 6), 256, 0, stream>>>(hbuf, WkT, kbuf, nullptr, nullptr, 768, 768, flagp);
  gemm_bt<M_VT>   <<<dim3(64, 6), 256, 0, stream>>>(hbuf, WvT, vtb,  nullptr, nullptr, 768, 768, flagp);

  attn_kernel<<<dim3(64, 12, 2), 256, 0, stream>>>(qbuf, kbuf, vtb, obuf);

  gemm_bt<M_RES>  <<<dim3(64, 6), 256, 0, stream>>>(obuf, WoT, x1b, x, nullptr, 768, 768, flagp);

  ln_kernel<<<ROWS, 256, 0, stream>>>(x1b, ln2s, ln2b, hbuf, flagp);

  gemm_bt<M_BRELU><<<dim3(64, 24), 256, 0, stream>>>(hbuf, W1T, tbuf, nullptr, b1, 3072, 768, flagp);
  gemm_bt<M_BRES> <<<dim3(64, 6),  256, 0, stream>>>(tbuf, W2T, d_out, x1b, b2, 768, 3072, flagp);
}

// Round 4
// 540.112 us; speedup vs baseline: 1.6473x; 1.6473x over previous
//
#include <hip/hip_runtime.h>
#include <stdint.h>

// ===================== problem constants =====================
constexpr int D_MODEL = 768;
constexpr int SEQ     = 4096;
constexpr int NHEAD   = 12;
constexpr int HDIM    = 64;
constexpr int BATCH   = 2;
constexpr int DFF     = 3072;
constexpr int ROWS    = BATCH * SEQ;   // 8192

typedef __attribute__((ext_vector_type(8))) __bf16 bfrag;
typedef __attribute__((ext_vector_type(4))) float  f32x4;

#define MFMA16(a, b, c) __builtin_amdgcn_mfma_f32_16x16x32_bf16((a), (b), (c), 0, 0, 0)
#define AS1(p) ((__attribute__((address_space(1))) void*)(uintptr_t)(p))
#define AS3(p) ((__attribute__((address_space(3))) void*)(p))

__device__ __forceinline__ float b2f(short s) {
  union { unsigned u; float f; } c;
  c.u = ((unsigned)(unsigned short)s) << 16;
  return c.f;
}
__device__ __forceinline__ short f2b(float f) {
  union { float f; unsigned u; } c;
  c.f = f;
  unsigned r = c.u + 0x7fffu + ((c.u >> 16) & 1u);  // RNE (finite inputs only)
  return (short)(r >> 16);
}
// dtype-flexible external load/store (flag: 1 = fp32, 0 = bf16)
__device__ __forceinline__ float ldf(const void* p, size_t i, bool f32) {
  return f32 ? ((const float*)p)[i] : b2f(((const short*)p)[i]);
}
__device__ __forceinline__ void stf(void* p, size_t i, bool f32, float v) {
  if (f32) ((float*)p)[i] = v;
  else     ((short*)p)[i] = f2b(v);
}

// ===================== dtype probe =====================
__global__ void probe_kernel(const unsigned short* __restrict__ s, int* __restrict__ flag) {
  *flag = (s[0] == 0x3F80u) ? 0 : 1;
}

// ===================== static BigBird plan (constexpr MT19937 == np.random.RandomState(0)) =====================
struct PlanT { int v[64][8]; };

struct MTRng {
  unsigned mt[624];
  int mti;
  constexpr MTRng() : mt{}, mti(624) {
    mt[0] = 0u;
    for (int i = 1; i < 624; ++i)
      mt[i] = 1812433253u * (mt[i-1] ^ (mt[i-1] >> 30)) + (unsigned)i;
  }
  constexpr unsigned next() {
    if (mti >= 624) {
      for (int i = 0; i < 624; ++i) {
        unsigned y = (mt[i] & 0x80000000u) | (mt[(i+1) % 624] & 0x7fffffffu);
        unsigned v = mt[(i+397) % 624] ^ (y >> 1);
        if (y & 1u) v ^= 0x9908b0dfu;
        mt[i] = v;
      }
      mti = 0;
    }
    unsigned y = mt[mti++];
    y ^= y >> 11;
    y ^= (y << 7)  & 0x9d2c5680u;
    y ^= (y << 15) & 0xefc60000u;
    y ^= y >> 18;
    return y;
  }
  constexpr unsigned interval(unsigned mx) {
    unsigned mask = mx;
    mask |= mask >> 1; mask |= mask >> 2; mask |= mask >> 4;
    mask |= mask >> 8; mask |= mask >> 16;
    unsigned v = next() & mask;
    while (v > mx) v = next() & mask;
    return v;
  }
};

constexpr PlanT make_plan() {
  PlanT P{};
  MTRng rng{};
  for (int i = 1; i <= 62; ++i) {
    int cand[64] = {}; int n = 0;
    for (int j = 0; j < 64; ++j) {
      if (j == 0 || j == 63 || j == i-1 || j == i || j == i+1) continue;
      cand[n++] = j;
    }
    int perm[64] = {};
    for (int p = 0; p < n; ++p) perm[p] = p;
    for (int p = n - 1; p > 0; --p) {
      int j = (int)rng.interval((unsigned)p);
      int t = perm[p]; perm[p] = perm[j]; perm[j] = t;
    }
    P.v[i][0] = 0;  P.v[i][1] = 63; P.v[i][2] = i-1; P.v[i][3] = i; P.v[i][4] = i+1;
    P.v[i][5] = cand[perm[0]]; P.v[i][6] = cand[perm[1]]; P.v[i][7] = cand[perm[2]];
  }
  return P;
}
constexpr PlanT h_plan = make_plan();
__constant__ PlanT g_plan = h_plan;

// ===================== layernorm (external-dtype in, bf16 out) =====================
__global__ __launch_bounds__(256) void ln_kernel(
    const void* __restrict__ x, const void* __restrict__ sc,
    const void* __restrict__ bi, short* __restrict__ y,
    const int* __restrict__ flagp)
{
  const bool f32 = (*flagp != 0);
  const int row = blockIdx.x, tid = threadIdx.x;
  const size_t base = (size_t)row * D_MODEL;
  float v0 = ldf(x, base + tid,       f32);
  float v1 = ldf(x, base + tid + 256, f32);
  float v2 = ldf(x, base + tid + 512, f32);
  float s  = v0 + v1 + v2;
  float s2 = v0*v0 + v1*v1 + v2*v2;
  for (int off = 1; off < 64; off <<= 1) {
    s  += __shfl_xor(s,  off);
    s2 += __shfl_xor(s2, off);
  }
  __shared__ float red[8];
  if ((tid & 63) == 0) { red[tid >> 6] = s; red[4 + (tid >> 6)] = s2; }
  __syncthreads();
  s  = red[0] + red[1] + red[2] + red[3];
  s2 = red[4] + red[5] + red[6] + red[7];
  const float mu  = s * (1.f / 768.f);
  const float var = s2 * (1.f / 768.f) - mu * mu;
  const float rs  = rsqrtf(var + 1e-6f);
  short* yr = y + base;
  yr[tid]       = f2b((v0 - mu) * rs * ldf(sc, tid,       f32) + ldf(bi, tid,       f32));
  yr[tid + 256] = f2b((v1 - mu) * rs * ldf(sc, tid + 256, f32) + ldf(bi, tid + 256, f32));
  yr[tid + 512] = f2b((v2 - mu) * rs * ldf(sc, tid + 512, f32) + ldf(bi, tid + 512, f32));
}

// ===================== transpose external weight (R x C -> bf16 C x R) =====================
__global__ __launch_bounds__(256) void tr_kernel(
    const void* __restrict__ in, short* __restrict__ out, int R, int C,
    const int* __restrict__ flagp)
{
  const bool f32 = (*flagp != 0);
  __shared__ short tile[32][33];
  const int bx = blockIdx.x * 32, by = blockIdx.y * 32;
  const int tx = threadIdx.x, ty = threadIdx.y;
  for (int i = 0; i < 32; i += 8)
    tile[ty + i][tx] = f2b(ldf(in, (size_t)(by + ty + i) * C + bx + tx, f32));
  __syncthreads();
  for (int i = 0; i < 32; i += 8)
    out[(size_t)(bx + ty + i) * R + by + tx] = tile[tx][ty + i];
}

// ===================== GEMM: C[M,N] = A[M,K] @ Bt[N,K]^T, bf16 internal, fp32 acc =====================
// m97 structure: 128x128 tile, BK=32, global_load_lds width-16 staging.
enum { M_PLAIN = 0, M_SCALE = 1, M_VT = 2, M_RES = 3, M_BRELU = 4, M_BRES = 5 };

template <int MODE>
__global__ __launch_bounds__(256) void gemm_bt(
    const short* __restrict__ A, const short* __restrict__ Bt,
    void* __restrict__ Cv, const void* __restrict__ res,
    const void* __restrict__ bias, int N, int K,
    const int* __restrict__ flagp)
{
  const bool f32 = (*flagp != 0);
  alignas(16) __shared__ short As[128 * 32];
  alignas(16) __shared__ short Bs[128 * 32];
  const int tid = threadIdx.x;
  const int wave = tid >> 6, lane = tid & 63;
  const int quad = lane >> 4, l15 = lane & 15;
  const int m0 = blockIdx.x * 128, n0 = blockIdx.y * 128;
  const int mw = (wave & 1) * 64, nw = (wave >> 1) * 64;

  f32x4 acc[4][4];
#pragma unroll
  for (int i = 0; i < 4; ++i)
#pragma unroll
    for (int j = 0; j < 4; ++j) acc[i][j] = f32x4{0.f, 0.f, 0.f, 0.f};

  // staging: lane i of wave w covers LDS bytes [w*2048 + i*16) — matches HW lane*16B rule
  const int srow = wave * 32 + (lane >> 2);
  const int scol = (lane & 3) * 8;
  const size_t arow = (size_t)(m0 + srow) * K + scol;
  const size_t brow = (size_t)(n0 + srow) * K + scol;

  for (int k0 = 0; k0 < K; k0 += 32) {
    __syncthreads();  // previous tile consumed
    __builtin_amdgcn_global_load_lds(AS1(A  + arow + k0),                AS3(As + (wave*32     ) * 32), 16, 0, 0);
    __builtin_amdgcn_global_load_lds(AS1(A  + arow + k0 + (size_t)16*K), AS3(As + (wave*32 + 16) * 32), 16, 0, 0);
    __builtin_amdgcn_global_load_lds(AS1(Bt + brow + k0),                AS3(Bs + (wave*32     ) * 32), 16, 0, 0);
    __builtin_amdgcn_global_load_lds(AS1(Bt + brow + k0 + (size_t)16*K), AS3(Bs + (wave*32 + 16) * 32), 16, 0, 0);
    __syncthreads();  // staging complete (compiler drains vmcnt before barrier)
    bfrag af[4], bfv[4];
#pragma unroll
    for (int mt = 0; mt < 4; ++mt) af[mt]  = *(const bfrag*)(As + (mw + mt*16 + l15) * 32 + quad * 8);
#pragma unroll
    for (int nt = 0; nt < 4; ++nt) bfv[nt] = *(const bfrag*)(Bs + (nw + nt*16 + l15) * 32 + quad * 8);
#pragma unroll
    for (int mt = 0; mt < 4; ++mt)
#pragma unroll
      for (int nt = 0; nt < 4; ++nt)
        acc[mt][nt] = MFMA16(af[mt], bfv[nt], acc[mt][nt]);
  }

  // epilogue: C/D layout col = lane&15, row = quad*4 + reg  [m89-verified]
#pragma unroll
  for (int mt = 0; mt < 4; ++mt) {
#pragma unroll
    for (int nt = 0; nt < 4; ++nt) {
#pragma unroll
      for (int r = 0; r < 4; ++r) {
        const int gm = m0 + mw + mt*16 + quad*4 + r;
        const int gn = n0 + nw + nt*16 + l15;
        const size_t ci = (size_t)gm * N + gn;
        float v = acc[mt][nt][r];
        if (MODE == M_SCALE) v *= 0.125f;
        if (MODE == M_RES)   v += ldf(res, ci, f32);
        if (MODE == M_BRELU) { v += ldf(bias, gn, f32); v = v > 0.f ? v : 0.f; }
        if (MODE == M_BRES)  v += ldf(bias, gn, f32) + ldf(res, ci, f32);
        if (MODE == M_VT) {
          const int bb = gm >> 12, l = gm & 4095, hh = gn >> 6, hd = gn & 63;
          ((short*)Cv)[(((size_t)(bb * NHEAD + hh)) * HDIM + hd) * SEQ + l] = f2b(v);
        } else if (MODE == M_RES || MODE == M_BRES) {
          stf(Cv, ci, f32, v);        // d_out: external dtype
        } else {
          ((short*)Cv)[ci] = f2b(v);  // internal bf16
        }
      }
    }
  }
}

// ===================== flash-style BigBird attention (uniform 8 K-blocks per block) =====================
// grid (item=78, head=12, batch=2). items 0..61: middle qb=item+1 (plan, direct write).
// items 62..77: global qb 0 / 63 split into 8 partials of 8 consecutive K-blocks each.
__global__ __launch_bounds__(256) void attn_kernel(
    const short* __restrict__ q, const short* __restrict__ k,
    const short* __restrict__ vt, short* __restrict__ o,
    short* __restrict__ Opart, float* __restrict__ ml)
{
  alignas(16) __shared__ short Pbuf[4][16 * 64];  // per-wave P tile (A-layout); no cross-wave sharing
  const int xi = blockIdx.x, h = blockIdx.y, b = blockIdx.z;
  const int tid = threadIdx.x, wave = tid >> 6, lane = tid & 63;
  const int quad = lane >> 4, l15 = lane & 15;

  int qb, part = 0, g = 0;
  bool partial;
  if (xi < 62) { qb = xi + 1; partial = false; }
  else { const int t = xi - 62; g = t >> 3; part = t & 7; qb = g ? 63 : 0; partial = true; }

  const short* qp = q + (size_t)(b * SEQ + qb * 64 + wave * 16 + l15) * D_MODEL + h * HDIM;
  const bfrag qf0 = *(const bfrag*)(qp + quad * 8);
  const bfrag qf1 = *(const bfrag*)(qp + 32 + quad * 8);

  const short* kb_base = k  + (size_t)b * SEQ * D_MODEL + h * HDIM;
  const short* vt_base = vt + ((size_t)(b * NHEAD + h)) * HDIM * SEQ;

  float m_r[4], l_r[4];
  f32x4 oacc[4];
#pragma unroll
  for (int r = 0; r < 4; ++r) { m_r[r] = -1e9f; l_r[r] = 0.f; }
#pragma unroll
  for (int nt = 0; nt < 4; ++nt) oacc[nt] = f32x4{0.f, 0.f, 0.f, 0.f};

  short* pb = &Pbuf[wave][0];

  for (int it = 0; it < 8; ++it) {
    const int kbk = partial ? (part * 8 + it) : g_plan.v[qb][it];

    // ---- S = Q K^T (16 x 64) ----
    f32x4 sacc[4];
#pragma unroll
    for (int nt = 0; nt < 4; ++nt) sacc[nt] = f32x4{0.f, 0.f, 0.f, 0.f};
    {
      const short* kr = kb_base + ((size_t)kbk * 64 + l15) * D_MODEL + quad * 8;
#pragma unroll
      for (int nt = 0; nt < 4; ++nt) {
        const bfrag kf0 = *(const bfrag*)(kr + (size_t)nt * 16 * D_MODEL);
        const bfrag kf1 = *(const bfrag*)(kr + (size_t)nt * 16 * D_MODEL + 32);
        sacc[nt] = MFMA16(qf0, kf0, sacc[nt]);
        sacc[nt] = MFMA16(qf1, kf1, sacc[nt]);
      }
    }

    // ---- online softmax (row = quad*4 + r, reduce over lane&15) ----
    float alpha[4];
#pragma unroll
    for (int r = 0; r < 4; ++r) {
      float v = fmaxf(fmaxf(sacc[0][r], sacc[1][r]), fmaxf(sacc[2][r], sacc[3][r]));
      v = fmaxf(v, __shfl_xor(v, 1));
      v = fmaxf(v, __shfl_xor(v, 2));
      v = fmaxf(v, __shfl_xor(v, 4));
      v = fmaxf(v, __shfl_xor(v, 8));
      const float mn = fmaxf(m_r[r], v);
      alpha[r] = __expf(m_r[r] - mn);
      m_r[r] = mn;
    }
    float psum[4] = {0.f, 0.f, 0.f, 0.f};
#pragma unroll
    for (int nt = 0; nt < 4; ++nt)
#pragma unroll
      for (int r = 0; r < 4; ++r) {
        const float p = __expf(sacc[nt][r] - m_r[r]);
        sacc[nt][r] = p;
        psum[r] += p;
      }
#pragma unroll
    for (int r = 0; r < 4; ++r) {
      float v = psum[r];
      v += __shfl_xor(v, 1); v += __shfl_xor(v, 2);
      v += __shfl_xor(v, 4); v += __shfl_xor(v, 8);
      l_r[r] = l_r[r] * alpha[r] + v;
    }

    // ---- P: C-layout -> A-layout via per-wave LDS (no barriers: wave-private buffer,
    //      within-wave RAW/WAR ordered by compiler lgkmcnt waits) ----
#pragma unroll
    for (int nt = 0; nt < 4; ++nt)
#pragma unroll
      for (int r = 0; r < 4; ++r)
        pb[(quad * 4 + r) * 64 + nt * 16 + l15] = f2b(sacc[nt][r]);

    // ---- O = alpha*O + P V ----
#pragma unroll
    for (int nt = 0; nt < 4; ++nt)
#pragma unroll
      for (int r = 0; r < 4; ++r) oacc[nt][r] *= alpha[r];
    const short* vp = vt_base + (size_t)kbk * 64 + quad * 8;
#pragma unroll
    for (int s = 0; s < 2; ++s) {
      const bfrag pf = *(const bfrag*)(pb + l15 * 64 + s * 32 + quad * 8);
#pragma unroll
      for (int nt = 0; nt < 4; ++nt) {
        const bfrag vf = *(const bfrag*)(vp + (size_t)(nt * 16 + l15) * SEQ + s * 32);
        oacc[nt] = MFMA16(pf, vf, oacc[nt]);
      }
    }
  }

  if (!partial) {
    short* op = o + (size_t)(b * SEQ + qb * 64 + wave * 16) * D_MODEL + h * HDIM;
#pragma unroll
    for (int r = 0; r < 4; ++r) {
      const float inv = 1.f / l_r[r];
#pragma unroll
      for (int nt = 0; nt < 4; ++nt)
        op[(size_t)(quad * 4 + r) * D_MODEL + nt * 16 + l15] = f2b(oacc[nt][r] * inv);
    }
  } else {
    const int pi = ((b * NHEAD + h) * 2 + g) * 8 + part;
    short* Op = Opart + (size_t)pi * 4096;
    float* mp = ml + (size_t)pi * 128;
#pragma unroll
    for (int r = 0; r < 4; ++r) {
      const int row = wave * 16 + quad * 4 + r;
#pragma unroll
      for (int nt = 0; nt < 4; ++nt)
        Op[row * 64 + nt * 16 + l15] = f2b(oacc[nt][r]);
      if (l15 == 0) { mp[row] = m_r[r]; mp[64 + row] = l_r[r]; }
    }
  }
}

// ===================== merge partials for global q-blocks =====================
// grid 48 = (b*12 + h)*2 + g; 256 threads, 16 elems each (64x64 tile).
__global__ __launch_bounds__(256) void attn_merge(
    const short* __restrict__ Opart, const float* __restrict__ ml,
    short* __restrict__ o)
{
  const int bi = blockIdx.x;
  const int g = bi & 1, h = (bi >> 1) % NHEAD, b = bi / (2 * NHEAD);
  const int qb = g ? 63 : 0;
  const int pi0 = bi * 8;
#pragma unroll
  for (int e = 0; e < 16; ++e) {
    const int idx = threadIdx.x + e * 256;
    const int r = idx >> 6, c = idx & 63;
    float ms = -1e9f;
#pragma unroll
    for (int p = 0; p < 8; ++p) ms = fmaxf(ms, ml[(size_t)(pi0 + p) * 128 + r]);
    float lsum = 0.f, osum = 0.f;
#pragma unroll
    for (int p = 0; p < 8; ++p) {
      const float w = __expf(ml[(size_t)(pi0 + p) * 128 + r] - ms);
      lsum += w * ml[(size_t)(pi0 + p) * 128 + 64 + r];
      osum += w * b2f(Opart[(size_t)(pi0 + p) * 4096 + idx]);
    }
    o[(size_t)(b * SEQ + qb * 64 + r) * D_MODEL + h * HDIM + c] = f2b(osum / lsum);
  }
}

// ===================== launch =====================
extern "C" void kernel_launch(void* const* d_in, const int* in_sizes, int n_in,
                              void* d_out, int out_size, void* d_ws, size_t ws_size,
                              hipStream_t stream) {
  (void)in_sizes; (void)n_in; (void)out_size; (void)ws_size;
  const void* x    = d_in[0];
  const void* ln1s = d_in[1];
  const void* ln1b = d_in[2];
  const void* Wq   = d_in[3];
  const void* Wk   = d_in[4];
  const void* Wv   = d_in[5];
  const void* Wo   = d_in[6];
  const void* ln2s = d_in[7];
  const void* ln2b = d_in[8];
  const void* W1   = d_in[9];
  const void* b1   = d_in[10];
  const void* W2   = d_in[11];
  const void* b2   = d_in[12];

  // ws layout (~77.1 MiB): flag | weightsT (14.2) | hbuf (12.6) | BIG 4x12.6 (tbuf)
  int*   flagp = (int*)d_ws;
  short* WqT  = (short*)((char*)d_ws + 256);
  short* WkT  = WqT  + 768 * 768;
  short* WvT  = WkT  + 768 * 768;
  short* WoT  = WvT  + 768 * 768;
  short* W1T  = WoT  + 768 * 768;          // (3072,768)
  short* W2T  = W1T  + (size_t)3072 * 768; // (768,3072)
  short* hbuf = W2T  + (size_t)3072 * 768;
  short* qbuf = hbuf + (size_t)ROWS * D_MODEL;
  short* kbuf = qbuf + (size_t)ROWS * D_MODEL;
  short* vtb  = kbuf + (size_t)ROWS * D_MODEL;
  short* obuf = vtb  + (size_t)ROWS * D_MODEL;
  short* tbuf = qbuf;   // MLP intermediate spans qbuf..obuf (4*ROWS*D_MODEL == ROWS*DFF)
  void*  x1b  = d_out;  // attn + x residual lives in d_out (external dtype)
  // attention partials live in hbuf (dead between QKV GEMMs and ln2): 384*4096 shorts + 384*128 floats ~= 3.3 MB
  short* Opart = hbuf;
  float* mlbuf = (float*)(hbuf + (size_t)384 * 4096);

  probe_kernel<<<1, 1, 0, stream>>>((const unsigned short*)ln1s, flagp);

  const dim3 trb(32, 8);
  tr_kernel<<<dim3(24, 24), trb, 0, stream>>>(Wq, WqT, 768, 768, flagp);
  tr_kernel<<<dim3(24, 24), trb, 0, stream>>>(Wk, WkT, 768, 768, flagp);
  tr_kernel<<<dim3(24, 24), trb, 0, stream>>>(Wv, WvT, 768, 768, flagp);
  tr_kernel<<<dim3(24, 24), trb, 0, stream>>>(Wo, WoT, 768, 768, flagp);
  tr_kernel<<<dim3(96, 24), trb, 0, stream>>>(W1, W1T, 768, 3072, flagp);
  tr_kernel<<<dim3(24, 96), trb, 0, stream>>>(W2, W2T, 3072, 768, flagp);

  ln_kernel<<<ROWS, 256, 0, stream>>>(x, ln1s, ln1b, hbuf, flagp);

  gemm_bt<M_SCALE><<<dim3(64, 6), 256, 0, stream>>>(hbuf, WqT, qbuf, nullptr, nullptr, 768, 768, flagp);
  gemm_bt<M_PLAIN><<<dim3(64, 6), 256, 0, stream>>>(hbuf, WkT, kbuf, nullptr, nullptr, 768, 768, flagp);
  gemm_bt<M_VT>   <<<dim3(64, 6), 256, 0, stream>>>(hbuf, WvT, vtb,  nullptr, nullptr, 768, 768, flagp);

  attn_kernel<<<dim3(78, 12, 2), 256, 0, stream>>>(qbuf, kbuf, vtb, obuf, Opart, mlbuf);
  attn_merge<<<48, 256, 0, stream>>>(Opart, mlbuf, obuf);

  gemm_bt<M_RES>  <<<dim3(64, 6), 256, 0, stream>>>(obuf, WoT, x1b, x, nullptr, 768, 768, flagp);

  ln_kernel<<<ROWS, 256, 0, stream>>>(x1b, ln2s, ln2b, hbuf, flagp);

  gemm_bt<M_BRELU><<<dim3(64, 24), 256, 0, stream>>>(hbuf, W1T, tbuf, nullptr, b1, 3072, 768, flagp);
  gemm_bt<M_BRES> <<<dim3(64, 6),  256, 0, stream>>>(tbuf, W2T, d_out, x1b, b2, 768, 3072, flagp);
}

// Round 5
// 471.224 us; speedup vs baseline: 1.8882x; 1.1462x over previous
//
#include <hip/hip_runtime.h>
#include <stdint.h>

// ===================== problem constants =====================
constexpr int D_MODEL = 768;
constexpr int SEQ     = 4096;
constexpr int NHEAD   = 12;
constexpr int HDIM    = 64;
constexpr int BATCH   = 2;
constexpr int DFF     = 3072;
constexpr int ROWS    = BATCH * SEQ;   // 8192

typedef __attribute__((ext_vector_type(8))) __bf16 bfrag;
typedef __attribute__((ext_vector_type(4))) float  f32x4;

#define MFMA16(a, b, c) __builtin_amdgcn_mfma_f32_16x16x32_bf16((a), (b), (c), 0, 0, 0)
#define AS1(p) ((__attribute__((address_space(1))) void*)(uintptr_t)(p))
#define AS3(p) ((__attribute__((address_space(3))) void*)(p))

__device__ __forceinline__ float b2f(short s) {
  union { unsigned u; float f; } c;
  c.u = ((unsigned)(unsigned short)s) << 16;
  return c.f;
}
__device__ __forceinline__ short f2b(float f) {
  union { float f; unsigned u; } c;
  c.f = f;
  unsigned r = c.u + 0x7fffu + ((c.u >> 16) & 1u);  // RNE (finite inputs only)
  return (short)(r >> 16);
}

// ===================== static BigBird plan (constexpr MT19937 == np.random.RandomState(0)) =====================
struct PlanT { int v[64][8]; };

struct MTRng {
  unsigned mt[624];
  int mti;
  constexpr MTRng() : mt{}, mti(624) {
    mt[0] = 0u;
    for (int i = 1; i < 624; ++i)
      mt[i] = 1812433253u * (mt[i-1] ^ (mt[i-1] >> 30)) + (unsigned)i;
  }
  constexpr unsigned next() {
    if (mti >= 624) {
      for (int i = 0; i < 624; ++i) {
        unsigned y = (mt[i] & 0x80000000u) | (mt[(i+1) % 624] & 0x7fffffffu);
        unsigned v = mt[(i+397) % 624] ^ (y >> 1);
        if (y & 1u) v ^= 0x9908b0dfu;
        mt[i] = v;
      }
      mti = 0;
    }
    unsigned y = mt[mti++];
    y ^= y >> 11;
    y ^= (y << 7)  & 0x9d2c5680u;
    y ^= (y << 15) & 0xefc60000u;
    y ^= y >> 18;
    return y;
  }
  constexpr unsigned interval(unsigned mx) {
    unsigned mask = mx;
    mask |= mask >> 1; mask |= mask >> 2; mask |= mask >> 4;
    mask |= mask >> 8; mask |= mask >> 16;
    unsigned v = next() & mask;
    while (v > mx) v = next() & mask;
    return v;
  }
};

constexpr PlanT make_plan() {
  PlanT P{};
  MTRng rng{};
  for (int i = 1; i <= 62; ++i) {
    int cand[64] = {}; int n = 0;
    for (int j = 0; j < 64; ++j) {
      if (j == 0 || j == 63 || j == i-1 || j == i || j == i+1) continue;
      cand[n++] = j;
    }
    int perm[64] = {};
    for (int p = 0; p < n; ++p) perm[p] = p;
    for (int p = n - 1; p > 0; --p) {
      int j = (int)rng.interval((unsigned)p);
      int t = perm[p]; perm[p] = perm[j]; perm[j] = t;
    }
    P.v[i][0] = 0;  P.v[i][1] = 63; P.v[i][2] = i-1; P.v[i][3] = i; P.v[i][4] = i+1;
    P.v[i][5] = cand[perm[0]]; P.v[i][6] = cand[perm[1]]; P.v[i][7] = cand[perm[2]];
  }
  return P;
}
constexpr PlanT h_plan = make_plan();
__constant__ PlanT g_plan = h_plan;

// ===================== layernorm (fp32 in, bf16 out) =====================
__global__ __launch_bounds__(256) void ln_kernel(
    const float* __restrict__ x, const float* __restrict__ sc,
    const float* __restrict__ bi, short* __restrict__ y)
{
  const int row = blockIdx.x, tid = threadIdx.x;
  const size_t base = (size_t)row * D_MODEL;
  float v0 = x[base + tid], v1 = x[base + tid + 256], v2 = x[base + tid + 512];
  float s  = v0 + v1 + v2;
  float s2 = v0*v0 + v1*v1 + v2*v2;
  for (int off = 1; off < 64; off <<= 1) {
    s  += __shfl_xor(s,  off);
    s2 += __shfl_xor(s2, off);
  }
  __shared__ float red[8];
  if ((tid & 63) == 0) { red[tid >> 6] = s; red[4 + (tid >> 6)] = s2; }
  __syncthreads();
  s  = red[0] + red[1] + red[2] + red[3];
  s2 = red[4] + red[5] + red[6] + red[7];
  const float mu  = s * (1.f / 768.f);
  const float var = s2 * (1.f / 768.f) - mu * mu;
  const float rs  = rsqrtf(var + 1e-6f);
  short* yr = y + base;
  yr[tid]       = f2b((v0 - mu) * rs * sc[tid]       + bi[tid]);
  yr[tid + 256] = f2b((v1 - mu) * rs * sc[tid + 256] + bi[tid + 256]);
  yr[tid + 512] = f2b((v2 - mu) * rs * sc[tid + 512] + bi[tid + 512]);
}

// ===================== fused weight transposes (fp32 R x C -> bf16 C x R), 1 dispatch =====================
struct TrArgs { const float* src[6]; short* dst[6]; };

__global__ __launch_bounds__(256) void tr_all(TrArgs a) {
  __shared__ short tile[32][33];
  const int idx = blockIdx.x;
  int w, bx, by, Rr, Cc;
  if (idx < 2304)      { w = idx / 576; int t = idx % 576;  bx = t % 24; by = t / 24; Rr = 768;  Cc = 768;  }
  else if (idx < 4608) { w = 4;         int t = idx - 2304; bx = t % 96; by = t / 96; Rr = 768;  Cc = 3072; }
  else                 { w = 5;         int t = idx - 4608; bx = t % 24; by = t / 24; Rr = 3072; Cc = 768;  }
  const float* in = a.src[w];
  short* out = a.dst[w];
  const int x0 = bx * 32, y0 = by * 32;
  const int tx = threadIdx.x & 31, ty = threadIdx.x >> 5;
  for (int i = 0; i < 32; i += 8)
    tile[ty + i][tx] = f2b(in[(size_t)(y0 + ty + i) * Cc + x0 + tx]);
  __syncthreads();
  for (int i = 0; i < 32; i += 8)
    out[(size_t)(x0 + ty + i) * Rr + y0 + tx] = tile[tx][ty + i];
}

// ===================== GEMM: C[M,N] = A[M,K] @ Bt[N,K]^T, bf16 internal, fp32 acc =====================
// m97 structure: 128x128 tile, BK=32, global_load_lds width-16 staging.
enum { M_QKV = 0, M_RES = 3, M_BRELU = 4, M_BRES = 5 };

template <int MODE>
__global__ __launch_bounds__(256) void gemm_bt(
    const short* __restrict__ A, const short* __restrict__ Bt,
    void* __restrict__ Cv, short* __restrict__ C2, short* __restrict__ C3,
    const float* __restrict__ res, const float* __restrict__ bias, int N, int K)
{
  alignas(16) __shared__ short As[128 * 32];
  alignas(16) __shared__ short Bs[128 * 32];
  const int tid = threadIdx.x;
  const int wave = tid >> 6, lane = tid & 63;
  const int quad = lane >> 4, l15 = lane & 15;
  const int m0 = blockIdx.x * 128, n0 = blockIdx.y * 128;
  const int mw = (wave & 1) * 64, nw = (wave >> 1) * 64;

  f32x4 acc[4][4];
#pragma unroll
  for (int i = 0; i < 4; ++i)
#pragma unroll
    for (int j = 0; j < 4; ++j) acc[i][j] = f32x4{0.f, 0.f, 0.f, 0.f};

  const int srow = wave * 32 + (lane >> 2);
  const int scol = (lane & 3) * 8;
  const size_t arow = (size_t)(m0 + srow) * K + scol;
  const size_t brow = (size_t)(n0 + srow) * K + scol;

  for (int k0 = 0; k0 < K; k0 += 32) {
    __syncthreads();
    __builtin_amdgcn_global_load_lds(AS1(A  + arow + k0),                AS3(As + (wave*32     ) * 32), 16, 0, 0);
    __builtin_amdgcn_global_load_lds(AS1(A  + arow + k0 + (size_t)16*K), AS3(As + (wave*32 + 16) * 32), 16, 0, 0);
    __builtin_amdgcn_global_load_lds(AS1(Bt + brow + k0),                AS3(Bs + (wave*32     ) * 32), 16, 0, 0);
    __builtin_amdgcn_global_load_lds(AS1(Bt + brow + k0 + (size_t)16*K), AS3(Bs + (wave*32 + 16) * 32), 16, 0, 0);
    __syncthreads();
    bfrag af[4], bfv[4];
#pragma unroll
    for (int mt = 0; mt < 4; ++mt) af[mt]  = *(const bfrag*)(As + (mw + mt*16 + l15) * 32 + quad * 8);
#pragma unroll
    for (int nt = 0; nt < 4; ++nt) bfv[nt] = *(const bfrag*)(Bs + (nw + nt*16 + l15) * 32 + quad * 8);
#pragma unroll
    for (int mt = 0; mt < 4; ++mt)
#pragma unroll
      for (int nt = 0; nt < 4; ++nt)
        acc[mt][nt] = MFMA16(af[mt], bfv[nt], acc[mt][nt]);
  }

  // epilogue: C/D layout col = lane&15, row = quad*4 + reg  [m89-verified]
#pragma unroll
  for (int mt = 0; mt < 4; ++mt) {
#pragma unroll
    for (int nt = 0; nt < 4; ++nt) {
#pragma unroll
      for (int r = 0; r < 4; ++r) {
        const int gm = m0 + mw + mt*16 + quad*4 + r;
        const int gn = n0 + nw + nt*16 + l15;
        float v = acc[mt][nt][r];
        if (MODE == M_QKV) {
          // segment 0: Q (scaled), 1: K, 2: V (scattered transposed)
          const int seg = gn / 768, gn2 = gn - seg * 768;
          if (seg == 0)      ((short*)Cv)[(size_t)gm * 768 + gn2] = f2b(v * 0.125f);
          else if (seg == 1) C2[(size_t)gm * 768 + gn2] = f2b(v);
          else {
            const int bb = gm >> 12, l = gm & 4095, hh = gn2 >> 6, hd = gn2 & 63;
            C3[(((size_t)(bb * NHEAD + hh)) * HDIM + hd) * SEQ + l] = f2b(v);
          }
        } else {
          const size_t ci = (size_t)gm * N + gn;
          if (MODE == M_RES)   { ((float*)Cv)[ci] = v + res[ci]; }
          if (MODE == M_BRELU) { v += bias[gn]; ((short*)Cv)[ci] = f2b(v > 0.f ? v : 0.f); }
          if (MODE == M_BRES)  { ((float*)Cv)[ci] = v + bias[gn] + res[ci]; }
        }
      }
    }
  }
}

// ===================== flash-style BigBird attention, 2-way unrolled K-loop =====================
// grid (item=78, head=12, batch=2). items 0..61: middle qb=item+1 (plan). 62..77: global qb 0/63
// split into 8 partials x 8 consecutive K-blocks. 4 waves; wave w owns q-rows [w*16, w*16+16).
constexpr int PSTR = 72;  // P-tile row stride (shorts); 64 would make b128 reads 16-way bank-conflicted

__global__ __launch_bounds__(256) void attn_kernel(
    const short* __restrict__ q, const short* __restrict__ k,
    const short* __restrict__ vt, short* __restrict__ o,
    short* __restrict__ Opart, float* __restrict__ ml)
{
  alignas(16) __shared__ short Pbuf[4][2 * 16 * PSTR];  // per-wave, 2 tiles (barrier-free)
  const int xi = blockIdx.x, h = blockIdx.y, b = blockIdx.z;
  const int tid = threadIdx.x, wave = tid >> 6, lane = tid & 63;
  const int quad = lane >> 4, l15 = lane & 15;

  int qb, part = 0, g = 0;
  bool partial;
  if (xi < 62) { qb = xi + 1; partial = false; }
  else { const int t = xi - 62; g = t >> 3; part = t & 7; qb = g ? 63 : 0; partial = true; }

  const short* qp = q + (size_t)(b * SEQ + qb * 64 + wave * 16 + l15) * D_MODEL + h * HDIM;
  const bfrag qf0 = *(const bfrag*)(qp + quad * 8);
  const bfrag qf1 = *(const bfrag*)(qp + 32 + quad * 8);

  const short* kb_base = k  + (size_t)b * SEQ * D_MODEL + h * HDIM;
  const short* vt_base = vt + ((size_t)(b * NHEAD + h)) * HDIM * SEQ;

  float m_r[4], l_r[4];
  f32x4 oacc[4];
#pragma unroll
  for (int r = 0; r < 4; ++r) { m_r[r] = -1e9f; l_r[r] = 0.f; }
#pragma unroll
  for (int nt = 0; nt < 4; ++nt) oacc[nt] = f32x4{0.f, 0.f, 0.f, 0.f};

  short* pb = &Pbuf[wave][0];

  for (int it = 0; it < 4; ++it) {
    const int k0i = partial ? (part * 8 + 2*it)     : g_plan.v[qb][2*it];
    const int k1i = partial ? (part * 8 + 2*it + 1) : g_plan.v[qb][2*it + 1];

    // ---- S0, S1 = Q K^T for two independent key blocks (ILP) ----
    f32x4 s0[4], s1[4];
#pragma unroll
    for (int nt = 0; nt < 4; ++nt) { s0[nt] = f32x4{0.f,0.f,0.f,0.f}; s1[nt] = f32x4{0.f,0.f,0.f,0.f}; }
    {
      const short* kr0 = kb_base + ((size_t)k0i * 64 + l15) * D_MODEL + quad * 8;
      const short* kr1 = kb_base + ((size_t)k1i * 64 + l15) * D_MODEL + quad * 8;
#pragma unroll
      for (int nt = 0; nt < 4; ++nt) {
        const bfrag ka0 = *(const bfrag*)(kr0 + (size_t)nt * 16 * D_MODEL);
        const bfrag ka1 = *(const bfrag*)(kr0 + (size_t)nt * 16 * D_MODEL + 32);
        const bfrag kb0 = *(const bfrag*)(kr1 + (size_t)nt * 16 * D_MODEL);
        const bfrag kb1 = *(const bfrag*)(kr1 + (size_t)nt * 16 * D_MODEL + 32);
        s0[nt] = MFMA16(qf0, ka0, s0[nt]); s0[nt] = MFMA16(qf1, ka1, s0[nt]);
        s1[nt] = MFMA16(qf0, kb0, s1[nt]); s1[nt] = MFMA16(qf1, kb1, s1[nt]);
      }
    }

    // ---- combined online softmax over 128 keys (row = quad*4 + r, reduce over lane&15) ----
    float alpha[4];
#pragma unroll
    for (int r = 0; r < 4; ++r) {
      float v = fmaxf(fmaxf(fmaxf(s0[0][r], s0[1][r]), fmaxf(s0[2][r], s0[3][r])),
                      fmaxf(fmaxf(s1[0][r], s1[1][r]), fmaxf(s1[2][r], s1[3][r])));
      v = fmaxf(v, __shfl_xor(v, 1));
      v = fmaxf(v, __shfl_xor(v, 2));
      v = fmaxf(v, __shfl_xor(v, 4));
      v = fmaxf(v, __shfl_xor(v, 8));
      const float mn = fmaxf(m_r[r], v);
      alpha[r] = __expf(m_r[r] - mn);
      m_r[r] = mn;
    }
    float psum[4] = {0.f, 0.f, 0.f, 0.f};
#pragma unroll
    for (int nt = 0; nt < 4; ++nt)
#pragma unroll
      for (int r = 0; r < 4; ++r) {
        const float p0 = __expf(s0[nt][r] - m_r[r]);
        const float p1 = __expf(s1[nt][r] - m_r[r]);
        s0[nt][r] = p0; s1[nt][r] = p1;
        psum[r] += p0 + p1;
      }
#pragma unroll
    for (int r = 0; r < 4; ++r) {
      float v = psum[r];
      v += __shfl_xor(v, 1); v += __shfl_xor(v, 2);
      v += __shfl_xor(v, 4); v += __shfl_xor(v, 8);
      l_r[r] = l_r[r] * alpha[r] + v;
    }

    // ---- P0,P1: C-layout -> A-layout via per-wave LDS (stride 72: conflict-free) ----
#pragma unroll
    for (int nt = 0; nt < 4; ++nt)
#pragma unroll
      for (int r = 0; r < 4; ++r) {
        pb[(quad * 4 + r) * PSTR + nt * 16 + l15]             = f2b(s0[nt][r]);
        pb[16 * PSTR + (quad * 4 + r) * PSTR + nt * 16 + l15] = f2b(s1[nt][r]);
      }

    // ---- O = alpha*O + P0 V0 + P1 V1 ----
#pragma unroll
    for (int nt = 0; nt < 4; ++nt)
#pragma unroll
      for (int r = 0; r < 4; ++r) oacc[nt][r] *= alpha[r];
    const short* vp0 = vt_base + (size_t)k0i * 64 + quad * 8;
    const short* vp1 = vt_base + (size_t)k1i * 64 + quad * 8;
#pragma unroll
    for (int s = 0; s < 2; ++s) {
      const bfrag pf0 = *(const bfrag*)(pb + l15 * PSTR + s * 32 + quad * 8);
      const bfrag pf1 = *(const bfrag*)(pb + 16 * PSTR + l15 * PSTR + s * 32 + quad * 8);
#pragma unroll
      for (int nt = 0; nt < 4; ++nt) {
        const bfrag vf0 = *(const bfrag*)(vp0 + (size_t)(nt * 16 + l15) * SEQ + s * 32);
        const bfrag vf1 = *(const bfrag*)(vp1 + (size_t)(nt * 16 + l15) * SEQ + s * 32);
        oacc[nt] = MFMA16(pf0, vf0, oacc[nt]);
        oacc[nt] = MFMA16(pf1, vf1, oacc[nt]);
      }
    }
  }

  if (!partial) {
    short* op = o + (size_t)(b * SEQ + qb * 64 + wave * 16) * D_MODEL + h * HDIM;
#pragma unroll
    for (int r = 0; r < 4; ++r) {
      const float inv = 1.f / l_r[r];
#pragma unroll
      for (int nt = 0; nt < 4; ++nt)
        op[(size_t)(quad * 4 + r) * D_MODEL + nt * 16 + l15] = f2b(oacc[nt][r] * inv);
    }
  } else {
    const int pi = ((b * NHEAD + h) * 2 + g) * 8 + part;
    short* Op = Opart + (size_t)pi * 4096;
    float* mp = ml + (size_t)pi * 128;
#pragma unroll
    for (int r = 0; r < 4; ++r) {
      const int row = wave * 16 + quad * 4 + r;
#pragma unroll
      for (int nt = 0; nt < 4; ++nt)
        Op[row * 64 + nt * 16 + l15] = f2b(oacc[nt][r]);
      if (l15 == 0) { mp[row] = m_r[r]; mp[64 + row] = l_r[r]; }
    }
  }
}

// ===================== merge partials for global q-blocks =====================
__global__ __launch_bounds__(256) void attn_merge(
    const short* __restrict__ Opart, const float* __restrict__ ml,
    short* __restrict__ o)
{
  const int bi = blockIdx.x;
  const int g = bi & 1, h = (bi >> 1) % NHEAD, b = bi / (2 * NHEAD);
  const int qb = g ? 63 : 0;
  const int pi0 = bi * 8;
#pragma unroll
  for (int e = 0; e < 16; ++e) {
    const int idx = threadIdx.x + e * 256;
    const int r = idx >> 6, c = idx & 63;
    float ms = -1e9f;
#pragma unroll
    for (int p = 0; p < 8; ++p) ms = fmaxf(ms, ml[(size_t)(pi0 + p) * 128 + r]);
    float lsum = 0.f, osum = 0.f;
#pragma unroll
    for (int p = 0; p < 8; ++p) {
      const float w = __expf(ml[(size_t)(pi0 + p) * 128 + r] - ms);
      lsum += w * ml[(size_t)(pi0 + p) * 128 + 64 + r];
      osum += w * b2f(Opart[(size_t)(pi0 + p) * 4096 + idx]);
    }
    o[(size_t)(b * SEQ + qb * 64 + r) * D_MODEL + h * HDIM + c] = f2b(osum / lsum);
  }
}

// ===================== launch =====================
extern "C" void kernel_launch(void* const* d_in, const int* in_sizes, int n_in,
                              void* d_out, int out_size, void* d_ws, size_t ws_size,
                              hipStream_t stream) {
  (void)in_sizes; (void)n_in; (void)out_size; (void)ws_size;
  const float* x    = (const float*)d_in[0];
  const float* ln1s = (const float*)d_in[1];
  const float* ln1b = (const float*)d_in[2];
  const float* Wq   = (const float*)d_in[3];
  const float* Wk   = (const float*)d_in[4];
  const float* Wv   = (const float*)d_in[5];
  const float* Wo   = (const float*)d_in[6];
  const float* ln2s = (const float*)d_in[7];
  const float* ln2b = (const float*)d_in[8];
  const float* W1   = (const float*)d_in[9];
  const float* b1   = (const float*)d_in[10];
  const float* W2   = (const float*)d_in[11];
  const float* b2   = (const float*)d_in[12];
  float* out = (float*)d_out;

  // ws layout (~77.1 MiB): weightsT (14.2) | hbuf (12.6) | BIG 4x12.6 (tbuf)
  short* WqT  = (short*)((char*)d_ws + 256);
  short* WkT  = WqT  + 768 * 768;          // WqT|WkT|WvT contiguous => fused QKV Bt[2304][768]
  short* WvT  = WkT  + 768 * 768;
  short* WoT  = WvT  + 768 * 768;
  short* W1T  = WoT  + 768 * 768;          // (3072,768)
  short* W2T  = W1T  + (size_t)3072 * 768; // (768,3072)
  short* hbuf = W2T  + (size_t)3072 * 768;
  short* qbuf = hbuf + (size_t)ROWS * D_MODEL;
  short* kbuf = qbuf + (size_t)ROWS * D_MODEL;
  short* vtb  = kbuf + (size_t)ROWS * D_MODEL;
  short* obuf = vtb  + (size_t)ROWS * D_MODEL;
  short* tbuf = qbuf;   // MLP intermediate spans qbuf..obuf (4*ROWS*D_MODEL == ROWS*DFF)
  // attention partials in hbuf (dead between QKV GEMM and ln2): 3.3 MB
  short* Opart = hbuf;
  float* mlbuf = (float*)(hbuf + (size_t)384 * 4096);

  TrArgs ta;
  ta.src[0] = Wq; ta.src[1] = Wk; ta.src[2] = Wv; ta.src[3] = Wo; ta.src[4] = W1; ta.src[5] = W2;
  ta.dst[0] = WqT; ta.dst[1] = WkT; ta.dst[2] = WvT; ta.dst[3] = WoT; ta.dst[4] = W1T; ta.dst[5] = W2T;
  tr_all<<<6912, 256, 0, stream>>>(ta);

  ln_kernel<<<ROWS, 256, 0, stream>>>(x, ln1s, ln1b, hbuf);

  gemm_bt<M_QKV><<<dim3(64, 18), 256, 0, stream>>>(hbuf, WqT, qbuf, kbuf, vtb, nullptr, nullptr, 2304, 768);

  attn_kernel<<<dim3(78, 12, 2), 256, 0, stream>>>(qbuf, kbuf, vtb, obuf, Opart, mlbuf);
  attn_merge<<<48, 256, 0, stream>>>(Opart, mlbuf, obuf);

  gemm_bt<M_RES><<<dim3(64, 6), 256, 0, stream>>>(obuf, WoT, out, nullptr, nullptr, x, nullptr, 768, 768);

  ln_kernel<<<ROWS, 256, 0, stream>>>(out, ln2s, ln2b, hbuf);

  gemm_bt<M_BRELU><<<dim3(64, 24), 256, 0, stream>>>(hbuf, W1T, tbuf, nullptr, nullptr, nullptr, b1, 3072, 768);
  gemm_bt<M_BRES> <<<dim3(64, 6),  256, 0, stream>>>(tbuf, W2T, out, nullptr, nullptr, out, b2, 768, 3072);
}

// Round 6
// 457.553 us; speedup vs baseline: 1.9446x; 1.0299x over previous
//
#include <hip/hip_runtime.h>
#include <stdint.h>

// ===================== problem constants =====================
constexpr int D_MODEL = 768;
constexpr int SEQ     = 4096;
constexpr int NHEAD   = 12;
constexpr int HDIM    = 64;
constexpr int BATCH   = 2;
constexpr int DFF     = 3072;
constexpr int ROWS    = BATCH * SEQ;   // 8192

typedef __attribute__((ext_vector_type(8))) __bf16 bfrag;
typedef __attribute__((ext_vector_type(4))) float  f32x4;

#define MFMA16(a, b, c) __builtin_amdgcn_mfma_f32_16x16x32_bf16((a), (b), (c), 0, 0, 0)
#define AS1(p) ((__attribute__((address_space(1))) void*)(uintptr_t)(p))
#define AS3(p) ((__attribute__((address_space(3))) void*)(p))

__device__ __forceinline__ float b2f(short s) {
  union { unsigned u; float f; } c;
  c.u = ((unsigned)(unsigned short)s) << 16;
  return c.f;
}
__device__ __forceinline__ short f2b(float f) {
  union { float f; unsigned u; } c;
  c.f = f;
  unsigned r = c.u + 0x7fffu + ((c.u >> 16) & 1u);  // RNE (finite inputs only)
  return (short)(r >> 16);
}

// ===================== static BigBird plan (constexpr MT19937 == np.random.RandomState(0)) =====================
struct PlanT { int v[64][8]; };

struct MTRng {
  unsigned mt[624];
  int mti;
  constexpr MTRng() : mt{}, mti(624) {
    mt[0] = 0u;
    for (int i = 1; i < 624; ++i)
      mt[i] = 1812433253u * (mt[i-1] ^ (mt[i-1] >> 30)) + (unsigned)i;
  }
  constexpr unsigned next() {
    if (mti >= 624) {
      for (int i = 0; i < 624; ++i) {
        unsigned y = (mt[i] & 0x80000000u) | (mt[(i+1) % 624] & 0x7fffffffu);
        unsigned v = mt[(i+397) % 624] ^ (y >> 1);
        if (y & 1u) v ^= 0x9908b0dfu;
        mt[i] = v;
      }
      mti = 0;
    }
    unsigned y = mt[mti++];
    y ^= y >> 11;
    y ^= (y << 7)  & 0x9d2c5680u;
    y ^= (y << 15) & 0xefc60000u;
    y ^= y >> 18;
    return y;
  }
  constexpr unsigned interval(unsigned mx) {
    unsigned mask = mx;
    mask |= mask >> 1; mask |= mask >> 2; mask |= mask >> 4;
    mask |= mask >> 8; mask |= mask >> 16;
    unsigned v = next() & mask;
    while (v > mx) v = next() & mask;
    return v;
  }
};

constexpr PlanT make_plan() {
  PlanT P{};
  MTRng rng{};
  for (int i = 1; i <= 62; ++i) {
    int cand[64] = {}; int n = 0;
    for (int j = 0; j < 64; ++j) {
      if (j == 0 || j == 63 || j == i-1 || j == i || j == i+1) continue;
      cand[n++] = j;
    }
    int perm[64] = {};
    for (int p = 0; p < n; ++p) perm[p] = p;
    for (int p = n - 1; p > 0; --p) {
      int j = (int)rng.interval((unsigned)p);
      int t = perm[p]; perm[p] = perm[j]; perm[j] = t;
    }
    P.v[i][0] = 0;  P.v[i][1] = 63; P.v[i][2] = i-1; P.v[i][3] = i; P.v[i][4] = i+1;
    P.v[i][5] = cand[perm[0]]; P.v[i][6] = cand[perm[1]]; P.v[i][7] = cand[perm[2]];
  }
  return P;
}
constexpr PlanT h_plan = make_plan();
__constant__ PlanT g_plan = h_plan;

// ===================== layernorm (fp32 in, bf16 out) =====================
__global__ __launch_bounds__(256) void ln_kernel(
    const float* __restrict__ x, const float* __restrict__ sc,
    const float* __restrict__ bi, short* __restrict__ y)
{
  const int row = blockIdx.x, tid = threadIdx.x;
  const size_t base = (size_t)row * D_MODEL;
  float v0 = x[base + tid], v1 = x[base + tid + 256], v2 = x[base + tid + 512];
  float s  = v0 + v1 + v2;
  float s2 = v0*v0 + v1*v1 + v2*v2;
  for (int off = 1; off < 64; off <<= 1) {
    s  += __shfl_xor(s,  off);
    s2 += __shfl_xor(s2, off);
  }
  __shared__ float red[8];
  if ((tid & 63) == 0) { red[tid >> 6] = s; red[4 + (tid >> 6)] = s2; }
  __syncthreads();
  s  = red[0] + red[1] + red[2] + red[3];
  s2 = red[4] + red[5] + red[6] + red[7];
  const float mu  = s * (1.f / 768.f);
  const float var = s2 * (1.f / 768.f) - mu * mu;
  const float rs  = rsqrtf(var + 1e-6f);
  short* yr = y + base;
  yr[tid]       = f2b((v0 - mu) * rs * sc[tid]       + bi[tid]);
  yr[tid + 256] = f2b((v1 - mu) * rs * sc[tid + 256] + bi[tid + 256]);
  yr[tid + 512] = f2b((v2 - mu) * rs * sc[tid + 512] + bi[tid + 512]);
}

// ===================== fused weight transposes (fp32 R x C -> bf16 C x R), 1 dispatch =====================
struct TrArgs { const float* src[6]; short* dst[6]; };

__global__ __launch_bounds__(256) void tr_all(TrArgs a) {
  __shared__ short tile[32][33];
  const int idx = blockIdx.x;
  int w, bx, by, Rr, Cc;
  if (idx < 2304)      { w = idx / 576; int t = idx % 576;  bx = t % 24; by = t / 24; Rr = 768;  Cc = 768;  }
  else if (idx < 4608) { w = 4;         int t = idx - 2304; bx = t % 96; by = t / 96; Rr = 768;  Cc = 3072; }
  else                 { w = 5;         int t = idx - 4608; bx = t % 24; by = t / 24; Rr = 3072; Cc = 768;  }
  const float* in = a.src[w];
  short* out = a.dst[w];
  const int x0 = bx * 32, y0 = by * 32;
  const int tx = threadIdx.x & 31, ty = threadIdx.x >> 5;
  for (int i = 0; i < 32; i += 8)
    tile[ty + i][tx] = f2b(in[(size_t)(y0 + ty + i) * Cc + x0 + tx]);
  __syncthreads();
  for (int i = 0; i < 32; i += 8)
    out[(size_t)(x0 + ty + i) * Rr + y0 + tx] = tile[tx][ty + i];
}

// ===================== GEMM: C[M,N] = A[M,K] @ Bt[N,K]^T, bf16 internal, fp32 acc =====================
// m97 structure: 128xTN tile, BK=32, global_load_lds width-16 staging. TN in {128, 64}.
enum { M_QKV = 0, M_RES = 3, M_BRELU = 4, M_BRES = 5 };

template <int MODE, int TN>
__global__ __launch_bounds__(256) void gemm_bt(
    const short* __restrict__ A, const short* __restrict__ Bt,
    void* __restrict__ Cv, short* __restrict__ C2, short* __restrict__ C3,
    const float* __restrict__ res, const float* __restrict__ bias, int N, int K)
{
  constexpr int NT = TN / 32;             // B-frags per wave (4 or 2)
  alignas(16) __shared__ short As[128 * 32];
  alignas(16) __shared__ short Bs[TN * 32];
  const int tid = threadIdx.x;
  const int wave = tid >> 6, lane = tid & 63;
  const int quad = lane >> 4, l15 = lane & 15;
  const int m0 = blockIdx.x * 128, n0 = blockIdx.y * TN;
  const int mw = (wave & 1) * 64, nw = (wave >> 1) * (TN / 2);

  f32x4 acc[4][NT];
#pragma unroll
  for (int i = 0; i < 4; ++i)
#pragma unroll
    for (int j = 0; j < NT; ++j) acc[i][j] = f32x4{0.f, 0.f, 0.f, 0.f};

  const int srow = wave * 32 + (lane >> 2);     // A staging row (also B for TN=128)
  const int scol = (lane & 3) * 8;
  const size_t arow = (size_t)(m0 + srow) * K + scol;
  const size_t brow128 = (size_t)(n0 + srow) * K + scol;
  const size_t brow64  = (size_t)(n0 + wave * 16 + (lane >> 2)) * K + scol;

  for (int k0 = 0; k0 < K; k0 += 32) {
    __syncthreads();
    __builtin_amdgcn_global_load_lds(AS1(A + arow + k0),                AS3(As + (wave*32     ) * 32), 16, 0, 0);
    __builtin_amdgcn_global_load_lds(AS1(A + arow + k0 + (size_t)16*K), AS3(As + (wave*32 + 16) * 32), 16, 0, 0);
    if constexpr (TN == 128) {
      __builtin_amdgcn_global_load_lds(AS1(Bt + brow128 + k0),                AS3(Bs + (wave*32     ) * 32), 16, 0, 0);
      __builtin_amdgcn_global_load_lds(AS1(Bt + brow128 + k0 + (size_t)16*K), AS3(Bs + (wave*32 + 16) * 32), 16, 0, 0);
    } else {
      __builtin_amdgcn_global_load_lds(AS1(Bt + brow64 + k0), AS3(Bs + (wave*16) * 32), 16, 0, 0);
    }
    __syncthreads();
    bfrag af[4], bfv[NT];
#pragma unroll
    for (int mt = 0; mt < 4; ++mt)  af[mt]  = *(const bfrag*)(As + (mw + mt*16 + l15) * 32 + quad * 8);
#pragma unroll
    for (int nt = 0; nt < NT; ++nt) bfv[nt] = *(const bfrag*)(Bs + (nw + nt*16 + l15) * 32 + quad * 8);
#pragma unroll
    for (int mt = 0; mt < 4; ++mt)
#pragma unroll
      for (int nt = 0; nt < NT; ++nt)
        acc[mt][nt] = MFMA16(af[mt], bfv[nt], acc[mt][nt]);
  }

  // epilogue: C/D layout col = lane&15, row = quad*4 + reg  [m89-verified]
#pragma unroll
  for (int mt = 0; mt < 4; ++mt) {
#pragma unroll
    for (int nt = 0; nt < NT; ++nt) {
#pragma unroll
      for (int r = 0; r < 4; ++r) {
        const int gm = m0 + mw + mt*16 + quad*4 + r;
        const int gn = n0 + nw + nt*16 + l15;
        float v = acc[mt][nt][r];
        if (MODE == M_QKV) {
          const int seg = gn / 768, gn2 = gn - seg * 768;
          if (seg == 0)      ((short*)Cv)[(size_t)gm * 768 + gn2] = f2b(v * 0.125f);
          else if (seg == 1) C2[(size_t)gm * 768 + gn2] = f2b(v);
          else {
            const int bb = gm >> 12, l = gm & 4095, hh = gn2 >> 6, hd = gn2 & 63;
            C3[(((size_t)(bb * NHEAD + hh)) * HDIM + hd) * SEQ + l] = f2b(v);
          }
        } else {
          const size_t ci = (size_t)gm * N + gn;
          if (MODE == M_RES)   { ((float*)Cv)[ci] = v + res[ci]; }
          if (MODE == M_BRELU) { v += bias[gn]; ((short*)Cv)[ci] = f2b(v > 0.f ? v : 0.f); }
          if (MODE == M_BRES)  { ((float*)Cv)[ci] = v + bias[gn] + res[ci]; }
        }
      }
    }
  }
}

// ===================== flash-style BigBird attention, 2-way unrolled K-loop =====================
// grid (item=78, head=12, batch=2). items 0..61: middle qb=item+1 (plan). 62..77: global qb 0/63
// split into 8 partials x 8 consecutive K-blocks. 4 waves; wave w owns q-rows [w*16, w*16+16).
// __launch_bounds__(256,3): VGPR cap ~170 so all 16 K-frag loads stay in flight (80-reg build
// serialized them at ~HBM latency each — the round-5 wall).
constexpr int PSTR = 72;  // P-tile row stride (shorts); 64 would be 16-way bank-conflicted

__global__ __launch_bounds__(256, 3) void attn_kernel(
    const short* __restrict__ q, const short* __restrict__ k,
    const short* __restrict__ vt, short* __restrict__ o,
    short* __restrict__ Opart, float* __restrict__ ml)
{
  alignas(16) __shared__ short Pbuf[4][2 * 16 * PSTR];  // per-wave, 2 tiles (barrier-free)
  const int xi = blockIdx.x, h = blockIdx.y, b = blockIdx.z;
  const int tid = threadIdx.x, wave = tid >> 6, lane = tid & 63;
  const int quad = lane >> 4, l15 = lane & 15;

  int qb, part = 0, g = 0;
  bool partial;
  if (xi < 62) { qb = xi + 1; partial = false; }
  else { const int t = xi - 62; g = t >> 3; part = t & 7; qb = g ? 63 : 0; partial = true; }

  const short* qp = q + (size_t)(b * SEQ + qb * 64 + wave * 16 + l15) * D_MODEL + h * HDIM;
  const bfrag qf0 = *(const bfrag*)(qp + quad * 8);
  const bfrag qf1 = *(const bfrag*)(qp + 32 + quad * 8);

  const short* kb_base = k  + (size_t)b * SEQ * D_MODEL + h * HDIM;
  const short* vt_base = vt + ((size_t)(b * NHEAD + h)) * HDIM * SEQ;

  float m_r[4], l_r[4];
  f32x4 oacc[4];
#pragma unroll
  for (int r = 0; r < 4; ++r) { m_r[r] = -1e9f; l_r[r] = 0.f; }
#pragma unroll
  for (int nt = 0; nt < 4; ++nt) oacc[nt] = f32x4{0.f, 0.f, 0.f, 0.f};

  short* pb = &Pbuf[wave][0];

  for (int it = 0; it < 4; ++it) {
    const int k0i = partial ? (part * 8 + 2*it)     : g_plan.v[qb][2*it];
    const int k1i = partial ? (part * 8 + 2*it + 1) : g_plan.v[qb][2*it + 1];

    // ---- batch-issue all 16 K-frag loads (independent; need the VGPR headroom) ----
    const short* kr0 = kb_base + ((size_t)k0i * 64 + l15) * D_MODEL + quad * 8;
    const short* kr1 = kb_base + ((size_t)k1i * 64 + l15) * D_MODEL + quad * 8;
    bfrag ka[4][2], kb[4][2];
#pragma unroll
    for (int nt = 0; nt < 4; ++nt) {
      ka[nt][0] = *(const bfrag*)(kr0 + (size_t)nt * 16 * D_MODEL);
      ka[nt][1] = *(const bfrag*)(kr0 + (size_t)nt * 16 * D_MODEL + 32);
      kb[nt][0] = *(const bfrag*)(kr1 + (size_t)nt * 16 * D_MODEL);
      kb[nt][1] = *(const bfrag*)(kr1 + (size_t)nt * 16 * D_MODEL + 32);
    }

    // ---- S0, S1 = Q K^T ----
    f32x4 s0[4], s1[4];
#pragma unroll
    for (int nt = 0; nt < 4; ++nt) {
      s0[nt] = f32x4{0.f,0.f,0.f,0.f}; s1[nt] = f32x4{0.f,0.f,0.f,0.f};
      s0[nt] = MFMA16(qf0, ka[nt][0], s0[nt]); s0[nt] = MFMA16(qf1, ka[nt][1], s0[nt]);
      s1[nt] = MFMA16(qf0, kb[nt][0], s1[nt]); s1[nt] = MFMA16(qf1, kb[nt][1], s1[nt]);
    }

    // ---- issue V-frag loads now; softmax below covers their latency ----
    const short* vp0 = vt_base + (size_t)k0i * 64 + quad * 8;
    const short* vp1 = vt_base + (size_t)k1i * 64 + quad * 8;
    bfrag vfa[2][4], vfb[2][4];
#pragma unroll
    for (int s = 0; s < 2; ++s)
#pragma unroll
      for (int nt = 0; nt < 4; ++nt) {
        vfa[s][nt] = *(const bfrag*)(vp0 + (size_t)(nt * 16 + l15) * SEQ + s * 32);
        vfb[s][nt] = *(const bfrag*)(vp1 + (size_t)(nt * 16 + l15) * SEQ + s * 32);
      }

    // ---- combined online softmax over 128 keys (row = quad*4 + r, reduce over lane&15) ----
    float alpha[4];
#pragma unroll
    for (int r = 0; r < 4; ++r) {
      float v = fmaxf(fmaxf(fmaxf(s0[0][r], s0[1][r]), fmaxf(s0[2][r], s0[3][r])),
                      fmaxf(fmaxf(s1[0][r], s1[1][r]), fmaxf(s1[2][r], s1[3][r])));
      v = fmaxf(v, __shfl_xor(v, 1));
      v = fmaxf(v, __shfl_xor(v, 2));
      v = fmaxf(v, __shfl_xor(v, 4));
      v = fmaxf(v, __shfl_xor(v, 8));
      const float mn = fmaxf(m_r[r], v);
      alpha[r] = __expf(m_r[r] - mn);
      m_r[r] = mn;
    }
    float psum[4] = {0.f, 0.f, 0.f, 0.f};
#pragma unroll
    for (int nt = 0; nt < 4; ++nt)
#pragma unroll
      for (int r = 0; r < 4; ++r) {
        const float p0 = __expf(s0[nt][r] - m_r[r]);
        const float p1 = __expf(s1[nt][r] - m_r[r]);
        s0[nt][r] = p0; s1[nt][r] = p1;
        psum[r] += p0 + p1;
      }
#pragma unroll
    for (int r = 0; r < 4; ++r) {
      float v = psum[r];
      v += __shfl_xor(v, 1); v += __shfl_xor(v, 2);
      v += __shfl_xor(v, 4); v += __shfl_xor(v, 8);
      l_r[r] = l_r[r] * alpha[r] + v;
    }

    // ---- P0,P1: C-layout -> A-layout via per-wave LDS (stride 72, 2-way max: free) ----
#pragma unroll
    for (int nt = 0; nt < 4; ++nt)
#pragma unroll
      for (int r = 0; r < 4; ++r) {
        pb[(quad * 4 + r) * PSTR + nt * 16 + l15]             = f2b(s0[nt][r]);
        pb[16 * PSTR + (quad * 4 + r) * PSTR + nt * 16 + l15] = f2b(s1[nt][r]);
      }

    // ---- O = alpha*O + P0 V0 + P1 V1 ----
#pragma unroll
    for (int nt = 0; nt < 4; ++nt)
#pragma unroll
      for (int r = 0; r < 4; ++r) oacc[nt][r] *= alpha[r];
#pragma unroll
    for (int s = 0; s < 2; ++s) {
      const bfrag pf0 = *(const bfrag*)(pb + l15 * PSTR + s * 32 + quad * 8);
      const bfrag pf1 = *(const bfrag*)(pb + 16 * PSTR + l15 * PSTR + s * 32 + quad * 8);
#pragma unroll
      for (int nt = 0; nt < 4; ++nt) {
        oacc[nt] = MFMA16(pf0, vfa[s][nt], oacc[nt]);
        oacc[nt] = MFMA16(pf1, vfb[s][nt], oacc[nt]);
      }
    }
  }

  if (!partial) {
    short* op = o + (size_t)(b * SEQ + qb * 64 + wave * 16) * D_MODEL + h * HDIM;
#pragma unroll
    for (int r = 0; r < 4; ++r) {
      const float inv = 1.f / l_r[r];
#pragma unroll
      for (int nt = 0; nt < 4; ++nt)
        op[(size_t)(quad * 4 + r) * D_MODEL + nt * 16 + l15] = f2b(oacc[nt][r] * inv);
    }
  } else {
    const int pi = ((b * NHEAD + h) * 2 + g) * 8 + part;
    short* Op = Opart + (size_t)pi * 4096;
    float* mp = ml + (size_t)pi * 128;
#pragma unroll
    for (int r = 0; r < 4; ++r) {
      const int row = wave * 16 + quad * 4 + r;
#pragma unroll
      for (int nt = 0; nt < 4; ++nt)
        Op[row * 64 + nt * 16 + l15] = f2b(oacc[nt][r]);
      if (l15 == 0) { mp[row] = m_r[r]; mp[64 + row] = l_r[r]; }
    }
  }
}

// ===================== merge partials for global q-blocks =====================
__global__ __launch_bounds__(256) void attn_merge(
    const short* __restrict__ Opart, const float* __restrict__ ml,
    short* __restrict__ o)
{
  const int bi = blockIdx.x;
  const int g = bi & 1, h = (bi >> 1) % NHEAD, b = bi / (2 * NHEAD);
  const int qb = g ? 63 : 0;
  const int pi0 = bi * 8;
#pragma unroll
  for (int e = 0; e < 16; ++e) {
    const int idx = threadIdx.x + e * 256;
    const int r = idx >> 6, c = idx & 63;
    float ms = -1e9f;
#pragma unroll
    for (int p = 0; p < 8; ++p) ms = fmaxf(ms, ml[(size_t)(pi0 + p) * 128 + r]);
    float lsum = 0.f, osum = 0.f;
#pragma unroll
    for (int p = 0; p < 8; ++p) {
      const float w = __expf(ml[(size_t)(pi0 + p) * 128 + r] - ms);
      lsum += w * ml[(size_t)(pi0 + p) * 128 + 64 + r];
      osum += w * b2f(Opart[(size_t)(pi0 + p) * 4096 + idx]);
    }
    o[(size_t)(b * SEQ + qb * 64 + r) * D_MODEL + h * HDIM + c] = f2b(osum / lsum);
  }
}

// ===================== launch =====================
extern "C" void kernel_launch(void* const* d_in, const int* in_sizes, int n_in,
                              void* d_out, int out_size, void* d_ws, size_t ws_size,
                              hipStream_t stream) {
  (void)in_sizes; (void)n_in; (void)out_size; (void)ws_size;
  const float* x    = (const float*)d_in[0];
  const float* ln1s = (const float*)d_in[1];
  const float* ln1b = (const float*)d_in[2];
  const float* Wq   = (const float*)d_in[3];
  const float* Wk   = (const float*)d_in[4];
  const float* Wv   = (const float*)d_in[5];
  const float* Wo   = (const float*)d_in[6];
  const float* ln2s = (const float*)d_in[7];
  const float* ln2b = (const float*)d_in[8];
  const float* W1   = (const float*)d_in[9];
  const float* b1   = (const float*)d_in[10];
  const float* W2   = (const float*)d_in[11];
  const float* b2   = (const float*)d_in[12];
  float* out = (float*)d_out;

  // ws layout (~77.1 MiB): weightsT (14.2) | hbuf (12.6) | BIG 4x12.6 (tbuf)
  short* WqT  = (short*)((char*)d_ws + 256);
  short* WkT  = WqT  + 768 * 768;          // WqT|WkT|WvT contiguous => fused QKV Bt[2304][768]
  short* WvT  = WkT  + 768 * 768;
  short* WoT  = WvT  + 768 * 768;
  short* W1T  = WoT  + 768 * 768;          // (3072,768)
  short* W2T  = W1T  + (size_t)3072 * 768; // (768,3072)
  short* hbuf = W2T  + (size_t)3072 * 768;
  short* qbuf = hbuf + (size_t)ROWS * D_MODEL;
  short* kbuf = qbuf + (size_t)ROWS * D_MODEL;
  short* vtb  = kbuf + (size_t)ROWS * D_MODEL;
  short* obuf = vtb  + (size_t)ROWS * D_MODEL;
  short* tbuf = qbuf;   // MLP intermediate spans qbuf..obuf (4*ROWS*D_MODEL == ROWS*DFF)
  // attention partials in hbuf (dead between QKV GEMM and ln2): 3.3 MB
  short* Opart = hbuf;
  float* mlbuf = (float*)(hbuf + (size_t)384 * 4096);

  TrArgs ta;
  ta.src[0] = Wq; ta.src[1] = Wk; ta.src[2] = Wv; ta.src[3] = Wo; ta.src[4] = W1; ta.src[5] = W2;
  ta.dst[0] = WqT; ta.dst[1] = WkT; ta.dst[2] = WvT; ta.dst[3] = WoT; ta.dst[4] = W1T; ta.dst[5] = W2T;
  tr_all<<<6912, 256, 0, stream>>>(ta);

  ln_kernel<<<ROWS, 256, 0, stream>>>(x, ln1s, ln1b, hbuf);

  gemm_bt<M_QKV, 128><<<dim3(64, 18), 256, 0, stream>>>(hbuf, WqT, qbuf, kbuf, vtb, nullptr, nullptr, 2304, 768);

  attn_kernel<<<dim3(78, 12, 2), 256, 0, stream>>>(qbuf, kbuf, vtb, obuf, Opart, mlbuf);
  attn_merge<<<48, 256, 0, stream>>>(Opart, mlbuf, obuf);

  gemm_bt<M_RES, 64><<<dim3(64, 12), 256, 0, stream>>>(obuf, WoT, out, nullptr, nullptr, x, nullptr, 768, 768);

  ln_kernel<<<ROWS, 256, 0, stream>>>(out, ln2s, ln2b, hbuf);

  gemm_bt<M_BRELU, 128><<<dim3(64, 24), 256, 0, stream>>>(hbuf, W1T, tbuf, nullptr, nullptr, nullptr, b1, 3072, 768);
  gemm_bt<M_BRES, 64> <<<dim3(64, 12), 256, 0, stream>>>(tbuf, W2T, out, nullptr, nullptr, out, b2, 768, 3072);
}

// Round 7
// 387.893 us; speedup vs baseline: 2.2938x; 1.1796x over previous
//
#include <hip/hip_runtime.h>
#include <stdint.h>

// ===================== problem constants =====================
constexpr int D_MODEL = 768;
constexpr int SEQ     = 4096;
constexpr int NHEAD   = 12;
constexpr int HDIM    = 64;
constexpr int BATCH   = 2;
constexpr int DFF     = 3072;
constexpr int ROWS    = BATCH * SEQ;   // 8192

typedef __attribute__((ext_vector_type(8))) __bf16 bfrag;
typedef __attribute__((ext_vector_type(8))) short  s16x8;
typedef __attribute__((ext_vector_type(4))) float  f32x4;

#define MFMA16(a, b, c) __builtin_amdgcn_mfma_f32_16x16x32_bf16((a), (b), (c), 0, 0, 0)
#define AS1(p) ((__attribute__((address_space(1))) void*)(uintptr_t)(p))
#define AS3(p) ((__attribute__((address_space(3))) void*)(p))

__device__ __forceinline__ float b2f(short s) {
  union { unsigned u; float f; } c;
  c.u = ((unsigned)(unsigned short)s) << 16;
  return c.f;
}
__device__ __forceinline__ short f2b(float f) {
  union { float f; unsigned u; } c;
  c.f = f;
  unsigned r = c.u + 0x7fffu + ((c.u >> 16) & 1u);  // RNE (finite inputs only)
  return (short)(r >> 16);
}

// ===================== static BigBird plan (constexpr MT19937 == np.random.RandomState(0)) =====================
struct PlanT { int v[64][8]; };

struct MTRng {
  unsigned mt[624];
  int mti;
  constexpr MTRng() : mt{}, mti(624) {
    mt[0] = 0u;
    for (int i = 1; i < 624; ++i)
      mt[i] = 1812433253u * (mt[i-1] ^ (mt[i-1] >> 30)) + (unsigned)i;
  }
  constexpr unsigned next() {
    if (mti >= 624) {
      for (int i = 0; i < 624; ++i) {
        unsigned y = (mt[i] & 0x80000000u) | (mt[(i+1) % 624] & 0x7fffffffu);
        unsigned v = mt[(i+397) % 624] ^ (y >> 1);
        if (y & 1u) v ^= 0x9908b0dfu;
        mt[i] = v;
      }
      mti = 0;
    }
    unsigned y = mt[mti++];
    y ^= y >> 11;
    y ^= (y << 7)  & 0x9d2c5680u;
    y ^= (y << 15) & 0xefc60000u;
    y ^= y >> 18;
    return y;
  }
  constexpr unsigned interval(unsigned mx) {
    unsigned mask = mx;
    mask |= mask >> 1; mask |= mask >> 2; mask |= mask >> 4;
    mask |= mask >> 8; mask |= mask >> 16;
    unsigned v = next() & mask;
    while (v > mx) v = next() & mask;
    return v;
  }
};

constexpr PlanT make_plan() {
  PlanT P{};
  MTRng rng{};
  for (int i = 1; i <= 62; ++i) {
    int cand[64] = {}; int n = 0;
    for (int j = 0; j < 64; ++j) {
      if (j == 0 || j == 63 || j == i-1 || j == i || j == i+1) continue;
      cand[n++] = j;
    }
    int perm[64] = {};
    for (int p = 0; p < n; ++p) perm[p] = p;
    for (int p = n - 1; p > 0; --p) {
      int j = (int)rng.interval((unsigned)p);
      int t = perm[p]; perm[p] = perm[j]; perm[j] = t;
    }
    P.v[i][0] = 0;  P.v[i][1] = 63; P.v[i][2] = i-1; P.v[i][3] = i; P.v[i][4] = i+1;
    P.v[i][5] = cand[perm[0]]; P.v[i][6] = cand[perm[1]]; P.v[i][7] = cand[perm[2]];
  }
  return P;
}
constexpr PlanT h_plan = make_plan();
__constant__ PlanT g_plan = h_plan;

// ===================== layernorm (fp32 in, bf16 out) =====================
__global__ __launch_bounds__(256) void ln_kernel(
    const float* __restrict__ x, const float* __restrict__ sc,
    const float* __restrict__ bi, short* __restrict__ y)
{
  const int row = blockIdx.x, tid = threadIdx.x;
  const size_t base = (size_t)row * D_MODEL;
  float v0 = x[base + tid], v1 = x[base + tid + 256], v2 = x[base + tid + 512];
  float s  = v0 + v1 + v2;
  float s2 = v0*v0 + v1*v1 + v2*v2;
  for (int off = 1; off < 64; off <<= 1) {
    s  += __shfl_xor(s,  off);
    s2 += __shfl_xor(s2, off);
  }
  __shared__ float red[8];
  if ((tid & 63) == 0) { red[tid >> 6] = s; red[4 + (tid >> 6)] = s2; }
  __syncthreads();
  s  = red[0] + red[1] + red[2] + red[3];
  s2 = red[4] + red[5] + red[6] + red[7];
  const float mu  = s * (1.f / 768.f);
  const float var = s2 * (1.f / 768.f) - mu * mu;
  const float rs  = rsqrtf(var + 1e-6f);
  short* yr = y + base;
  yr[tid]       = f2b((v0 - mu) * rs * sc[tid]       + bi[tid]);
  yr[tid + 256] = f2b((v1 - mu) * rs * sc[tid + 256] + bi[tid + 256]);
  yr[tid + 512] = f2b((v2 - mu) * rs * sc[tid + 512] + bi[tid + 512]);
}

// ===================== fused weight transposes (fp32 R x C -> bf16 C x R), 1 dispatch =====================
struct TrArgs { const float* src[6]; short* dst[6]; };

__global__ __launch_bounds__(256) void tr_all(TrArgs a) {
  __shared__ short tile[32][33];
  const int idx = blockIdx.x;
  int w, bx, by, Rr, Cc;
  if (idx < 2304)      { w = idx / 576; int t = idx % 576;  bx = t % 24; by = t / 24; Rr = 768;  Cc = 768;  }
  else if (idx < 4608) { w = 4;         int t = idx - 2304; bx = t % 96; by = t / 96; Rr = 768;  Cc = 3072; }
  else                 { w = 5;         int t = idx - 4608; bx = t % 24; by = t / 24; Rr = 3072; Cc = 768;  }
  const float* in = a.src[w];
  short* out = a.dst[w];
  const int x0 = bx * 32, y0 = by * 32;
  const int tx = threadIdx.x & 31, ty = threadIdx.x >> 5;
  for (int i = 0; i < 32; i += 8)
    tile[ty + i][tx] = f2b(in[(size_t)(y0 + ty + i) * Cc + x0 + tx]);
  __syncthreads();
  for (int i = 0; i < 32; i += 8)
    out[(size_t)(x0 + ty + i) * Rr + y0 + tx] = tile[tx][ty + i];
}

// ===================== GEMM: C[M,N] = A[M,K] @ Bt[N,K]^T, bf16 internal, fp32 acc =====================
// m97 structure: 128xTN tile, BK=32, global_load_lds width-16 staging. TN in {128, 64}.
enum { M_QKV = 0, M_RES = 3, M_BRELU = 4, M_BRES = 5 };

template <int MODE, int TN>
__global__ __launch_bounds__(256) void gemm_bt(
    const short* __restrict__ A, const short* __restrict__ Bt,
    void* __restrict__ Cv, short* __restrict__ C2, short* __restrict__ C3,
    const float* __restrict__ res, const float* __restrict__ bias, int N, int K)
{
  constexpr int NT = TN / 32;             // B-frags per wave (4 or 2)
  alignas(16) __shared__ short As[128 * 32];
  alignas(16) __shared__ short Bs[TN * 32];
  const int tid = threadIdx.x;
  const int wave = tid >> 6, lane = tid & 63;
  const int quad = lane >> 4, l15 = lane & 15;
  const int m0 = blockIdx.x * 128, n0 = blockIdx.y * TN;
  const int mw = (wave & 1) * 64, nw = (wave >> 1) * (TN / 2);

  f32x4 acc[4][NT];
#pragma unroll
  for (int i = 0; i < 4; ++i)
#pragma unroll
    for (int j = 0; j < NT; ++j) acc[i][j] = f32x4{0.f, 0.f, 0.f, 0.f};

  const int srow = wave * 32 + (lane >> 2);
  const int scol = (lane & 3) * 8;
  const size_t arow = (size_t)(m0 + srow) * K + scol;
  const size_t brow128 = (size_t)(n0 + srow) * K + scol;
  const size_t brow64  = (size_t)(n0 + wave * 16 + (lane >> 2)) * K + scol;

  for (int k0 = 0; k0 < K; k0 += 32) {
    __syncthreads();
    __builtin_amdgcn_global_load_lds(AS1(A + arow + k0),                AS3(As + (wave*32     ) * 32), 16, 0, 0);
    __builtin_amdgcn_global_load_lds(AS1(A + arow + k0 + (size_t)16*K), AS3(As + (wave*32 + 16) * 32), 16, 0, 0);
    if constexpr (TN == 128) {
      __builtin_amdgcn_global_load_lds(AS1(Bt + brow128 + k0),                AS3(Bs + (wave*32     ) * 32), 16, 0, 0);
      __builtin_amdgcn_global_load_lds(AS1(Bt + brow128 + k0 + (size_t)16*K), AS3(Bs + (wave*32 + 16) * 32), 16, 0, 0);
    } else {
      __builtin_amdgcn_global_load_lds(AS1(Bt + brow64 + k0), AS3(Bs + (wave*16) * 32), 16, 0, 0);
    }
    __syncthreads();
    bfrag af[4], bfv[NT];
#pragma unroll
    for (int mt = 0; mt < 4; ++mt)  af[mt]  = *(const bfrag*)(As + (mw + mt*16 + l15) * 32 + quad * 8);
#pragma unroll
    for (int nt = 0; nt < NT; ++nt) bfv[nt] = *(const bfrag*)(Bs + (nw + nt*16 + l15) * 32 + quad * 8);
#pragma unroll
    for (int mt = 0; mt < 4; ++mt)
#pragma unroll
      for (int nt = 0; nt < NT; ++nt)
        acc[mt][nt] = MFMA16(af[mt], bfv[nt], acc[mt][nt]);
  }

  // epilogue: C/D layout col = lane&15, row = quad*4 + reg  [m89-verified]
#pragma unroll
  for (int mt = 0; mt < 4; ++mt) {
#pragma unroll
    for (int nt = 0; nt < NT; ++nt) {
#pragma unroll
      for (int r = 0; r < 4; ++r) {
        const int gm = m0 + mw + mt*16 + quad*4 + r;
        const int gn = n0 + nw + nt*16 + l15;
        float v = acc[mt][nt][r];
        if (MODE == M_QKV) {
          const int seg = gn / 768, gn2 = gn - seg * 768;
          if (seg == 0)      ((short*)Cv)[(size_t)gm * 768 + gn2] = f2b(v * 0.125f);
          else if (seg == 1) C2[(size_t)gm * 768 + gn2] = f2b(v);
          else {
            const int bb = gm >> 12, l = gm & 4095, hh = gn2 >> 6, hd = gn2 & 63;
            C3[(((size_t)(bb * NHEAD + hh)) * HDIM + hd) * SEQ + l] = f2b(v);
          }
        } else {
          const size_t ci = (size_t)gm * N + gn;
          if (MODE == M_RES)   { ((float*)Cv)[ci] = v + res[ci]; }
          if (MODE == M_BRELU) { v += bias[gn]; ((short*)Cv)[ci] = f2b(v > 0.f ? v : 0.f); }
          if (MODE == M_BRES)  { ((float*)Cv)[ci] = v + bias[gn] + res[ci]; }
        }
      }
    }
  }
}

// ===================== flash-style BigBird attention =====================
// Block-cooperative K/V LDS staging (round-6 fix: all 4 waves were loading IDENTICAL
// K/V frags -> 4x redundant global traffic + serialized load chains). K0,K1,V0,V1 staged
// once per block into stride-68 padded LDS via register round-trip, prefetched one
// iteration ahead so global latency hides behind softmax+MFMA compute.
// grid (item=78, head=12, batch=2). items 0..61: middle qb=item+1 (plan). 62..77: global
// qb 0/63 split into 8 partials x 8 consecutive K-blocks.
constexpr int PSTR = 72;  // P-tile row stride (shorts): b128 reads 2-way max
constexpr int KSTR = 68;  // K/V stage row stride (shorts): reads 2-way, writes clean

__global__ __launch_bounds__(256, 3) void attn_kernel(
    const short* __restrict__ q, const short* __restrict__ k,
    const short* __restrict__ vt, short* __restrict__ o,
    short* __restrict__ Opart, float* __restrict__ ml)
{
  alignas(16) __shared__ short KV[4][64 * KSTR];        // K0,K1,V0,V1   (34816 B)
  alignas(16) __shared__ short Pbuf[4][2 * 16 * PSTR];  // per-wave P    (18432 B)
  const int xi = blockIdx.x, h = blockIdx.y, b = blockIdx.z;
  const int tid = threadIdx.x, wave = tid >> 6, lane = tid & 63;
  const int quad = lane >> 4, l15 = lane & 15;
  const int r8 = lane >> 3, g8 = lane & 7;              // staging: row-in-8, granule

  int qb, part = 0, g = 0;
  bool partial;
  if (xi < 62) { qb = xi + 1; partial = false; }
  else { const int t = xi - 62; g = t >> 3; part = t & 7; qb = g ? 63 : 0; partial = true; }

  const short* qp = q + (size_t)(b * SEQ + qb * 64 + wave * 16 + l15) * D_MODEL + h * HDIM;
  const bfrag qf0 = *(const bfrag*)(qp + quad * 8);
  const bfrag qf1 = *(const bfrag*)(qp + 32 + quad * 8);

  const short* kb_base = k  + (size_t)b * SEQ * D_MODEL + h * HDIM;
  const short* vt_base = vt + ((size_t)(b * NHEAD + h)) * HDIM * SEQ;

  // staging rows this lane covers: wave*16 + j*8 + r8 (j = 0,1)
  const int sr0 = wave * 16 + r8, sr1 = wave * 16 + 8 + r8;

  // key-block index for iteration t (clamped prefetch for t==4)
  auto kidx = [&](int t, int which) -> int {
    const int tt = t > 3 ? 3 : t;
    return partial ? (part * 8 + 2 * tt + which) : g_plan.v[qb][2 * tt + which];
  };
  auto load8 = [&](int k0i, int k1i, s16x8* R) {
    const short* ka = kb_base + (size_t)k0i * 64 * D_MODEL + g8 * 8;
    const short* kbp = kb_base + (size_t)k1i * 64 * D_MODEL + g8 * 8;
    const short* va = vt_base + (size_t)k0i * 64 + g8 * 8;
    const short* vb = vt_base + (size_t)k1i * 64 + g8 * 8;
    R[0] = *(const s16x8*)(ka  + (size_t)sr0 * D_MODEL);
    R[1] = *(const s16x8*)(ka  + (size_t)sr1 * D_MODEL);
    R[2] = *(const s16x8*)(kbp + (size_t)sr0 * D_MODEL);
    R[3] = *(const s16x8*)(kbp + (size_t)sr1 * D_MODEL);
    R[4] = *(const s16x8*)(va  + (size_t)sr0 * SEQ);
    R[5] = *(const s16x8*)(va  + (size_t)sr1 * SEQ);
    R[6] = *(const s16x8*)(vb  + (size_t)sr0 * SEQ);
    R[7] = *(const s16x8*)(vb  + (size_t)sr1 * SEQ);
  };

  float m_r[4], l_r[4];
  f32x4 oacc[4];
#pragma unroll
  for (int r = 0; r < 4; ++r) { m_r[r] = -1e9f; l_r[r] = 0.f; }
#pragma unroll
  for (int nt = 0; nt < 4; ++nt) oacc[nt] = f32x4{0.f, 0.f, 0.f, 0.f};

  short* pb = &Pbuf[wave][0];

  s16x8 R[8];
  load8(kidx(0, 0), kidx(0, 1), R);

  for (int it = 0; it < 4; ++it) {
    __syncthreads();  // all waves done reading previous KV tiles
#pragma unroll
    for (int bu = 0; bu < 4; ++bu) {
      *(s16x8*)(&KV[bu][sr0 * KSTR + g8 * 8]) = R[2 * bu];
      *(s16x8*)(&KV[bu][sr1 * KSTR + g8 * 8]) = R[2 * bu + 1];
    }
    __syncthreads();  // staging visible to all waves

    // prefetch next iteration's K/V into registers (consumed at next ds_write;
    // full compute phase below hides the latency)
    load8(kidx(it + 1, 0), kidx(it + 1, 1), R);

    // ---- S0, S1 = Q K^T from LDS ----
    f32x4 s0[4], s1[4];
#pragma unroll
    for (int nt = 0; nt < 4; ++nt) {
      const int fr = (nt * 16 + l15) * KSTR + quad * 8;
      const bfrag ka0 = *(const bfrag*)(&KV[0][fr]);
      const bfrag ka1 = *(const bfrag*)(&KV[0][fr + 32]);
      const bfrag kb0 = *(const bfrag*)(&KV[1][fr]);
      const bfrag kb1 = *(const bfrag*)(&KV[1][fr + 32]);
      s0[nt] = f32x4{0.f,0.f,0.f,0.f}; s1[nt] = f32x4{0.f,0.f,0.f,0.f};
      s0[nt] = MFMA16(qf0, ka0, s0[nt]); s0[nt] = MFMA16(qf1, ka1, s0[nt]);
      s1[nt] = MFMA16(qf0, kb0, s1[nt]); s1[nt] = MFMA16(qf1, kb1, s1[nt]);
    }

    // ---- combined online softmax over 128 keys (row = quad*4 + r, reduce over lane&15) ----
    float alpha[4];
#pragma unroll
    for (int r = 0; r < 4; ++r) {
      float v = fmaxf(fmaxf(fmaxf(s0[0][r], s0[1][r]), fmaxf(s0[2][r], s0[3][r])),
                      fmaxf(fmaxf(s1[0][r], s1[1][r]), fmaxf(s1[2][r], s1[3][r])));
      v = fmaxf(v, __shfl_xor(v, 1));
      v = fmaxf(v, __shfl_xor(v, 2));
      v = fmaxf(v, __shfl_xor(v, 4));
      v = fmaxf(v, __shfl_xor(v, 8));
      const float mn = fmaxf(m_r[r], v);
      alpha[r] = __expf(m_r[r] - mn);
      m_r[r] = mn;
    }
    float psum[4] = {0.f, 0.f, 0.f, 0.f};
#pragma unroll
    for (int nt = 0; nt < 4; ++nt)
#pragma unroll
      for (int r = 0; r < 4; ++r) {
        const float p0 = __expf(s0[nt][r] - m_r[r]);
        const float p1 = __expf(s1[nt][r] - m_r[r]);
        s0[nt][r] = p0; s1[nt][r] = p1;
        psum[r] += p0 + p1;
      }
#pragma unroll
    for (int r = 0; r < 4; ++r) {
      float v = psum[r];
      v += __shfl_xor(v, 1); v += __shfl_xor(v, 2);
      v += __shfl_xor(v, 4); v += __shfl_xor(v, 8);
      l_r[r] = l_r[r] * alpha[r] + v;
    }

    // ---- P0,P1: C-layout -> A-layout via per-wave LDS ----
#pragma unroll
    for (int nt = 0; nt < 4; ++nt)
#pragma unroll
      for (int r = 0; r < 4; ++r) {
        pb[(quad * 4 + r) * PSTR + nt * 16 + l15]             = f2b(s0[nt][r]);
        pb[16 * PSTR + (quad * 4 + r) * PSTR + nt * 16 + l15] = f2b(s1[nt][r]);
      }

    // ---- O = alpha*O + P0 V0 + P1 V1 (V from LDS) ----
#pragma unroll
    for (int nt = 0; nt < 4; ++nt)
#pragma unroll
      for (int r = 0; r < 4; ++r) oacc[nt][r] *= alpha[r];
#pragma unroll
    for (int s = 0; s < 2; ++s) {
      const bfrag pf0 = *(const bfrag*)(pb + l15 * PSTR + s * 32 + quad * 8);
      const bfrag pf1 = *(const bfrag*)(pb + 16 * PSTR + l15 * PSTR + s * 32 + quad * 8);
#pragma unroll
      for (int nt = 0; nt < 4; ++nt) {
        const int fr = (nt * 16 + l15) * KSTR + s * 32 + quad * 8;
        const bfrag vf0 = *(const bfrag*)(&KV[2][fr]);
        const bfrag vf1 = *(const bfrag*)(&KV[3][fr]);
        oacc[nt] = MFMA16(pf0, vf0, oacc[nt]);
        oacc[nt] = MFMA16(pf1, vf1, oacc[nt]);
      }
    }
  }

  if (!partial) {
    short* op = o + (size_t)(b * SEQ + qb * 64 + wave * 16) * D_MODEL + h * HDIM;
#pragma unroll
    for (int r = 0; r < 4; ++r) {
      const float inv = 1.f / l_r[r];
#pragma unroll
      for (int nt = 0; nt < 4; ++nt)
        op[(size_t)(quad * 4 + r) * D_MODEL + nt * 16 + l15] = f2b(oacc[nt][r] * inv);
    }
  } else {
    const int pi = ((b * NHEAD + h) * 2 + g) * 8 + part;
    short* Op = Opart + (size_t)pi * 4096;
    float* mp = ml + (size_t)pi * 128;
#pragma unroll
    for (int r = 0; r < 4; ++r) {
      const int row = wave * 16 + quad * 4 + r;
#pragma unroll
      for (int nt = 0; nt < 4; ++nt)
        Op[row * 64 + nt * 16 + l15] = f2b(oacc[nt][r]);
      if (l15 == 0) { mp[row] = m_r[r]; mp[64 + row] = l_r[r]; }
    }
  }
}

// ===================== merge partials for global q-blocks =====================
__global__ __launch_bounds__(256) void attn_merge(
    const short* __restrict__ Opart, const float* __restrict__ ml,
    short* __restrict__ o)
{
  const int bi = blockIdx.x;
  const int g = bi & 1, h = (bi >> 1) % NHEAD, b = bi / (2 * NHEAD);
  const int qb = g ? 63 : 0;
  const int pi0 = bi * 8;
#pragma unroll
  for (int e = 0; e < 16; ++e) {
    const int idx = threadIdx.x + e * 256;
    const int r = idx >> 6, c = idx & 63;
    float ms = -1e9f;
#pragma unroll
    for (int p = 0; p < 8; ++p) ms = fmaxf(ms, ml[(size_t)(pi0 + p) * 128 + r]);
    float lsum = 0.f, osum = 0.f;
#pragma unroll
    for (int p = 0; p < 8; ++p) {
      const float w = __expf(ml[(size_t)(pi0 + p) * 128 + r] - ms);
      lsum += w * ml[(size_t)(pi0 + p) * 128 + 64 + r];
      osum += w * b2f(Opart[(size_t)(pi0 + p) * 4096 + idx]);
    }
    o[(size_t)(b * SEQ + qb * 64 + r) * D_MODEL + h * HDIM + c] = f2b(osum / lsum);
  }
}

// ===================== launch =====================
extern "C" void kernel_launch(void* const* d_in, const int* in_sizes, int n_in,
                              void* d_out, int out_size, void* d_ws, size_t ws_size,
                              hipStream_t stream) {
  (void)in_sizes; (void)n_in; (void)out_size; (void)ws_size;
  const float* x    = (const float*)d_in[0];
  const float* ln1s = (const float*)d_in[1];
  const float* ln1b = (const float*)d_in[2];
  const float* Wq   = (const float*)d_in[3];
  const float* Wk   = (const float*)d_in[4];
  const float* Wv   = (const float*)d_in[5];
  const float* Wo   = (const float*)d_in[6];
  const float* ln2s = (const float*)d_in[7];
  const float* ln2b = (const float*)d_in[8];
  const float* W1   = (const float*)d_in[9];
  const float* b1   = (const float*)d_in[10];
  const float* W2   = (const float*)d_in[11];
  const float* b2   = (const float*)d_in[12];
  float* out = (float*)d_out;

  // ws layout (~77.1 MiB): weightsT (14.2) | hbuf (12.6) | BIG 4x12.6 (tbuf)
  short* WqT  = (short*)((char*)d_ws + 256);
  short* WkT  = WqT  + 768 * 768;          // WqT|WkT|WvT contiguous => fused QKV Bt[2304][768]
  short* WvT  = WkT  + 768 * 768;
  short* WoT  = WvT  + 768 * 768;
  short* W1T  = WoT  + 768 * 768;          // (3072,768)
  short* W2T  = W1T  + (size_t)3072 * 768; // (768,3072)
  short* hbuf = W2T  + (size_t)3072 * 768;
  short* qbuf = hbuf + (size_t)ROWS * D_MODEL;
  short* kbuf = qbuf + (size_t)ROWS * D_MODEL;
  short* vtb  = kbuf + (size_t)ROWS * D_MODEL;
  short* obuf = vtb  + (size_t)ROWS * D_MODEL;
  short* tbuf = qbuf;   // MLP intermediate spans qbuf..obuf (4*ROWS*D_MODEL == ROWS*DFF)
  // attention partials in hbuf (dead between QKV GEMM and ln2): 3.3 MB
  short* Opart = hbuf;
  float* mlbuf = (float*)(hbuf + (size_t)384 * 4096);

  TrArgs ta;
  ta.src[0] = Wq; ta.src[1] = Wk; ta.src[2] = Wv; ta.src[3] = Wo; ta.src[4] = W1; ta.src[5] = W2;
  ta.dst[0] = WqT; ta.dst[1] = WkT; ta.dst[2] = WvT; ta.dst[3] = WoT; ta.dst[4] = W1T; ta.dst[5] = W2T;
  tr_all<<<6912, 256, 0, stream>>>(ta);

  ln_kernel<<<ROWS, 256, 0, stream>>>(x, ln1s, ln1b, hbuf);

  gemm_bt<M_QKV, 128><<<dim3(64, 18), 256, 0, stream>>>(hbuf, WqT, qbuf, kbuf, vtb, nullptr, nullptr, 2304, 768);

  attn_kernel<<<dim3(78, 12, 2), 256, 0, stream>>>(qbuf, kbuf, vtb, obuf, Opart, mlbuf);
  attn_merge<<<48, 256, 0, stream>>>(Opart, mlbuf, obuf);

  gemm_bt<M_RES, 64><<<dim3(64, 12), 256, 0, stream>>>(obuf, WoT, out, nullptr, nullptr, x, nullptr, 768, 768);

  ln_kernel<<<ROWS, 256, 0, stream>>>(out, ln2s, ln2b, hbuf);

  gemm_bt<M_BRELU, 128><<<dim3(64, 24), 256, 0, stream>>>(hbuf, W1T, tbuf, nullptr, nullptr, nullptr, b1, 3072, 768);
  gemm_bt<M_BRES, 64> <<<dim3(64, 12), 256, 0, stream>>>(tbuf, W2T, out, nullptr, nullptr, out, b2, 768, 3072);
}